// Round 4
// baseline (1397.445 us; speedup 1.0000x reference)
//
#include <hip/hip_runtime.h>
#include <hip/hip_bf16.h>
#include <math.h>

#define NN 20000
#define NE 320000
#define NG 128
#define DD 64
#define FA 92
#define FF 128
#define NT (NE / 16)   // 16-edge MFMA tiles

typedef __attribute__((ext_vector_type(8))) short bf16x8;
typedef __attribute__((ext_vector_type(4))) float f32x4;

__device__ __forceinline__ float sp_(float x) {
    return fmaxf(x, 0.f) + __logf(1.f + __expf(-fabsf(x)));
}
__device__ __forceinline__ float sig_(float x) {
    return 1.f / (1.f + __expf(-x));
}
__device__ __forceinline__ unsigned short f2b(float x) {
    __hip_bfloat16 b = __float2bfloat16(x);
    return *reinterpret_cast<unsigned short*>(&b);
}

// ---------------- embedding: h = af @ emb_W + emb_b (fp32 + bf16 copy) ----------------
__global__ __launch_bounds__(256) void embed_k(const float* __restrict__ af,
                                               const float* __restrict__ W,
                                               const float* __restrict__ b,
                                               float* __restrict__ h,
                                               unsigned short* __restrict__ hb) {
    __shared__ float Ws[FA * DD]; // 23552 B
    for (int i = threadIdx.x * 4; i < FA * DD; i += 256 * 4)
        *(float4*)&Ws[i] = *(const float4*)&W[i];
    __syncthreads();
    int n = blockIdx.x * 256 + threadIdx.x;
    if (n >= NN) return;
    float acc[DD];
#pragma unroll
    for (int j = 0; j < DD; ++j) acc[j] = b[j];
    const float* row = af + (size_t)n * FA;
#pragma unroll 1
    for (int k4 = 0; k4 < FA / 4; ++k4) {
        float4 z = *(const float4*)(row + k4 * 4);
#pragma unroll
        for (int kk = 0; kk < 4; ++kk) {
            float a = ((const float*)&z)[kk];
            const float* wr = &Ws[(k4 * 4 + kk) * DD];
#pragma unroll
            for (int j = 0; j < DD; j += 4) {
                float4 w = *(const float4*)(wr + j);
                acc[j + 0] += a * w.x; acc[j + 1] += a * w.y;
                acc[j + 2] += a * w.z; acc[j + 3] += a * w.w;
            }
        }
    }
    float* o = h + (size_t)n * DD;
    unsigned short* ob = hb + (size_t)n * DD;
#pragma unroll
    for (int j = 0; j < DD; j += 4) {
        float4 v; v.x = acc[j]; v.y = acc[j + 1]; v.z = acc[j + 2]; v.w = acc[j + 3];
        *(float4*)(o + j) = v;
    }
#pragma unroll
    for (int j = 0; j < DD; ++j) ob[j] = f2b(acc[j]);
}

// ---------------- weight fragment prep: Wf[l][g][kt][nf][lane][i] bf16 ----------------
__global__ void prep_wf_k(const float* __restrict__ Wi, const float* __restrict__ Wu,
                          unsigned short* __restrict__ Wf) {
    int b = blockIdx.x;          // 0..5 : layer*2 + gate
    int l = b >> 1, g = b & 1;
    const float* W = (g ? Wu : Wi) + (size_t)l * 160 * DD;
    for (int f = threadIdx.x; f < 10240; f += 256) {
        int i = f & 7;
        int lane = (f >> 3) & 63;
        int nf = (f >> 9) & 3;
        int kt = f >> 11;
        int k = kt * 32 + 8 * (lane >> 4) + i;
        int col = nf * 16 + (lane & 15);
        Wf[(size_t)b * 10240 + f] = f2b(W[k * DD + col]);
    }
}

// ---------------- CSR build (sorted-by-dst edge order) ----------------
__global__ void cnt_edges_k(const int* __restrict__ dst, int* __restrict__ cnt) {
    int e = blockIdx.x * 256 + threadIdx.x;
    if (e < NE) atomicAdd(&cnt[dst[e]], 1);
}

__global__ __launch_bounds__(1024) void csr_scan_k(const int* __restrict__ cnt,
                                                   int* __restrict__ off,
                                                   int* __restrict__ cur) {
    __shared__ int part[1024];
    int t = threadIdx.x;
    int base = t * 20;
    int s = 0;
    for (int i = 0; i < 20; ++i) { int idx = base + i; if (idx < NN) s += cnt[idx]; }
    part[t] = s;
    __syncthreads();
    for (int ofs = 1; ofs < 1024; ofs <<= 1) {
        int v = (t >= ofs) ? part[t - ofs] : 0;
        __syncthreads();
        part[t] += v;
        __syncthreads();
    }
    int run = (t == 0) ? 0 : part[t - 1];
    for (int i = 0; i < 20; ++i) {
        int idx = base + i;
        if (idx < NN) { off[idx] = run; cur[idx] = run; run += cnt[idx]; }
    }
    if (t == 1023) off[NN] = run;
}

__global__ void fill_edges_k(const int* __restrict__ src, const int* __restrict__ dst,
                             int* __restrict__ cur, int* __restrict__ lst,
                             int* __restrict__ ssrc, int* __restrict__ sdst) {
    int e = blockIdx.x * 256 + threadIdx.x;
    if (e < NE) {
        int d = dst[e];
        int p = atomicAdd(&cur[d], 1);
        lst[p] = e;
        ssrc[p] = src[e];
        sdst[p] = d;
    }
}

// ---------------- RBF in sorted order: rbfs[p][32] bf16 ----------------
__global__ void rbfs_k(const float* __restrict__ bond, const int* __restrict__ lst,
                       unsigned short* __restrict__ rbfs) {
    int p = blockIdx.x * 256 + threadIdx.x;
    if (p >= NE) return;
    float d = bond[lst[p]];
    unsigned short tmp[32];
#pragma unroll
    for (int k = 0; k < 32; ++k) {
        float c = (float)k * (8.0f / 31.0f);
        float u = d - c;
        tmp[k] = f2b(__expf(-3.875f * u * u));
    }
#pragma unroll
    for (int q = 0; q < 4; ++q)
        *(bf16x8*)&rbfs[(size_t)p * 32 + q * 8] = *(const bf16x8*)&tmp[q * 8];
}

// ---------------- pass 1: edge-tiled MFMA, column stats only ----------------
__global__ __launch_bounds__(256, 4) void edge_stats_k(const unsigned short* __restrict__ hb,
                                                       const unsigned short* __restrict__ rbfs,
                                                       const unsigned short* __restrict__ Wf,
                                                       const int* __restrict__ ssrc,
                                                       const int* __restrict__ sdst,
                                                       float* __restrict__ stats) {
    __shared__ bf16x8 WfS[2560]; // 40 KB : [gate][kt][nf][lane]
    {
        const bf16x8* Wf8 = (const bf16x8*)Wf;
        for (int i = threadIdx.x; i < 2560; i += 256) WfS[i] = Wf8[i];
    }
    __syncthreads();

    const int lane = threadIdx.x & 63;
    const int r = lane & 15;
    const int c = lane >> 4;
    const int wid = (blockIdx.x * 256 + threadIdx.x) >> 6;
    const int nwaves = (gridDim.x * 256) >> 6;

    float sI[4] = {0.f, 0.f, 0.f, 0.f}, qI[4] = {0.f, 0.f, 0.f, 0.f};
    float sU[4] = {0.f, 0.f, 0.f, 0.f}, qU[4] = {0.f, 0.f, 0.f, 0.f};

    int tile = wid;
    int es = 0, ed = 0;
    if (tile < NT) { es = ssrc[tile * 16 + r]; ed = sdst[tile * 16 + r]; }

    while (tile < NT) {
        const int e0 = tile * 16;
        bf16x8 a0 = *(const bf16x8*)(hb + (size_t)es * DD + c * 8);
        bf16x8 a1 = *(const bf16x8*)(hb + (size_t)es * DD + 32 + c * 8);
        bf16x8 a2 = *(const bf16x8*)(hb + (size_t)ed * DD + c * 8);
        bf16x8 a3 = *(const bf16x8*)(hb + (size_t)ed * DD + 32 + c * 8);
        bf16x8 a4 = *(const bf16x8*)(rbfs + (size_t)e0 * 32 + r * 32 + c * 8);

        // prefetch next tile's indices (hides index load under MFMA)
        int ntile = tile + nwaves;
        int es_n = 0, ed_n = 0;
        if (ntile < NT) { es_n = ssrc[ntile * 16 + r]; ed_n = sdst[ntile * 16 + r]; }

        f32x4 accI[4], accU[4];
#pragma unroll
        for (int nf = 0; nf < 4; ++nf) {
            f32x4 z4 = {0.f, 0.f, 0.f, 0.f};
            accI[nf] = z4; accU[nf] = z4;
        }
#pragma unroll
        for (int kt = 0; kt < 5; ++kt) {
            bf16x8 a = (kt == 0) ? a0 : (kt == 1) ? a1 : (kt == 2) ? a2 : (kt == 3) ? a3 : a4;
#pragma unroll
            for (int nf = 0; nf < 4; ++nf) {
                bf16x8 bI = WfS[(kt * 4 + nf) * 64 + lane];
                accI[nf] = __builtin_amdgcn_mfma_f32_16x16x32_bf16(a, bI, accI[nf], 0, 0, 0);
                bf16x8 bU = WfS[1280 + (kt * 4 + nf) * 64 + lane];
                accU[nf] = __builtin_amdgcn_mfma_f32_16x16x32_bf16(a, bU, accU[nf], 0, 0, 0);
            }
        }
#pragma unroll
        for (int nf = 0; nf < 4; ++nf) {
#pragma unroll
            for (int j = 0; j < 4; ++j) {
                float vI = accI[nf][j];
                float vU = accU[nf][j];
                sI[nf] += vI; qI[nf] += vI * vI;
                sU[nf] += vU; qU[nf] += vU * vU;
            }
        }
        tile = ntile; es = es_n; ed = ed_n;
    }

#pragma unroll
    for (int nf = 0; nf < 4; ++nf) {
        float v;
        v = sI[nf]; v += __shfl_xor(v, 16, 64); v += __shfl_xor(v, 32, 64);
        if (lane < 16) unsafeAtomicAdd(&stats[nf * 16 + lane], v);
        v = qI[nf]; v += __shfl_xor(v, 16, 64); v += __shfl_xor(v, 32, 64);
        if (lane < 16) unsafeAtomicAdd(&stats[64 + nf * 16 + lane], v);
        v = sU[nf]; v += __shfl_xor(v, 16, 64); v += __shfl_xor(v, 32, 64);
        if (lane < 16) unsafeAtomicAdd(&stats[128 + nf * 16 + lane], v);
        v = qU[nf]; v += __shfl_xor(v, 16, 64); v += __shfl_xor(v, 32, 64);
        if (lane < 16) unsafeAtomicAdd(&stats[192 + nf * 16 + lane], v);
    }
}

// ---------------- finalize BN coefficients for gate/update; zero m-stats ----------------
__global__ void fin_iu_k(float* __restrict__ stats,
                         const float* __restrict__ gi, const float* __restrict__ bbi,
                         const float* __restrict__ gu, const float* __restrict__ bbu,
                         float* __restrict__ coeff) {
    int j = threadIdx.x; // 64
    const float invE = 1.f / (float)NE;
    float muI = stats[j] * invE;
    float varI = stats[64 + j] * invE - muI * muI;
    float sI = gi[j] * rsqrtf(varI + 1e-5f);
    coeff[j] = sI;
    coeff[64 + j] = bbi[j] - muI * sI;
    float muU = stats[128 + j] * invE;
    float varU = stats[192 + j] * invE - muU * muU;
    float sU = gu[j] * rsqrtf(varU + 1e-5f);
    coeff[128 + j] = sU;
    coeff[192 + j] = bbu[j] - muU * sU;
    stats[256 + j] = 0.f;  // msum
    stats[320 + j] = 0.f;  // msq
}

// ---------------- pass 2: edge-tiled MFMA recompute + BN + act + segmented atomic -> m ----------------
__global__ __launch_bounds__(256, 4) void edge_apply_k(const unsigned short* __restrict__ hb,
                                                       const unsigned short* __restrict__ rbfs,
                                                       const unsigned short* __restrict__ Wf,
                                                       const int* __restrict__ ssrc,
                                                       const int* __restrict__ sdst,
                                                       const float* __restrict__ coeff,
                                                       float* __restrict__ m) {
    __shared__ bf16x8 WfS[2560]; // 40 KB
    {
        const bf16x8* Wf8 = (const bf16x8*)Wf;
        for (int i = threadIdx.x; i < 2560; i += 256) WfS[i] = Wf8[i];
    }
    __syncthreads();

    const int lane = threadIdx.x & 63;
    const int r = lane & 15;
    const int c = lane >> 4;
    const int wid = (blockIdx.x * 256 + threadIdx.x) >> 6;
    const int nwaves = (gridDim.x * 256) >> 6;

    float sI[4], tI[4], sU[4], tU[4];
#pragma unroll
    for (int nf = 0; nf < 4; ++nf) {
        sI[nf] = coeff[nf * 16 + r];
        tI[nf] = coeff[64 + nf * 16 + r];
        sU[nf] = coeff[128 + nf * 16 + r];
        tU[nf] = coeff[192 + nf * 16 + r];
    }

    int tile = wid;
    int es = 0, ed = 0;
    if (tile < NT) { es = ssrc[tile * 16 + r]; ed = sdst[tile * 16 + r]; }

    while (tile < NT) {
        const int e0 = tile * 16;
        bf16x8 a0 = *(const bf16x8*)(hb + (size_t)es * DD + c * 8);
        bf16x8 a1 = *(const bf16x8*)(hb + (size_t)es * DD + 32 + c * 8);
        bf16x8 a2 = *(const bf16x8*)(hb + (size_t)ed * DD + c * 8);
        bf16x8 a3 = *(const bf16x8*)(hb + (size_t)ed * DD + 32 + c * 8);
        bf16x8 a4 = *(const bf16x8*)(rbfs + (size_t)e0 * 32 + r * 32 + c * 8);

        // node ids for this c-group's 4 output rows (uniform across r-lanes)
        int nid0 = sdst[e0 + c * 4 + 0];
        int nid1 = sdst[e0 + c * 4 + 1];
        int nid2 = sdst[e0 + c * 4 + 2];
        int nid3 = sdst[e0 + c * 4 + 3];

        int ntile = tile + nwaves;
        int es_n = 0, ed_n = 0;
        if (ntile < NT) { es_n = ssrc[ntile * 16 + r]; ed_n = sdst[ntile * 16 + r]; }

        f32x4 accI[4], accU[4];
#pragma unroll
        for (int nf = 0; nf < 4; ++nf) {
            f32x4 z4 = {0.f, 0.f, 0.f, 0.f};
            accI[nf] = z4; accU[nf] = z4;
        }
#pragma unroll
        for (int kt = 0; kt < 5; ++kt) {
            bf16x8 a = (kt == 0) ? a0 : (kt == 1) ? a1 : (kt == 2) ? a2 : (kt == 3) ? a3 : a4;
#pragma unroll
            for (int nf = 0; nf < 4; ++nf) {
                bf16x8 bI = WfS[(kt * 4 + nf) * 64 + lane];
                accI[nf] = __builtin_amdgcn_mfma_f32_16x16x32_bf16(a, bI, accI[nf], 0, 0, 0);
                bf16x8 bU = WfS[1280 + (kt * 4 + nf) * 64 + lane];
                accU[nf] = __builtin_amdgcn_mfma_f32_16x16x32_bf16(a, bU, accU[nf], 0, 0, 0);
            }
        }
        // BN + act; run-compressed atomic accumulation into m (rows sorted by dst)
#pragma unroll
        for (int nf = 0; nf < 4; ++nf) {
            const int colg = nf * 16 + r;
            float A0 = sig_(accI[nf][0] * sI[nf] + tI[nf]) * sp_(accU[nf][0] * sU[nf] + tU[nf]);
            float A1 = sig_(accI[nf][1] * sI[nf] + tI[nf]) * sp_(accU[nf][1] * sU[nf] + tU[nf]);
            float A2 = sig_(accI[nf][2] * sI[nf] + tI[nf]) * sp_(accU[nf][2] * sU[nf] + tU[nf]);
            float A3 = sig_(accI[nf][3] * sI[nf] + tI[nf]) * sp_(accU[nf][3] * sU[nf] + tU[nf]);
            float run = A0;
            int cn = nid0;
            if (nid1 == cn) run += A1;
            else { unsafeAtomicAdd(&m[(size_t)cn * DD + colg], run); run = A1; cn = nid1; }
            if (nid2 == cn) run += A2;
            else { unsafeAtomicAdd(&m[(size_t)cn * DD + colg], run); run = A2; cn = nid2; }
            if (nid3 == cn) run += A3;
            else { unsafeAtomicAdd(&m[(size_t)cn * DD + colg], run); run = A3; cn = nid3; }
            unsafeAtomicAdd(&m[(size_t)cn * DD + colg], run);
        }
        tile = ntile; es = es_n; ed = ed_n;
    }
}

// ---------------- m column stats: msum/msq over nodes ----------------
__global__ __launch_bounds__(256) void m_stats_k(const float* __restrict__ m,
                                                 float* __restrict__ msum,
                                                 float* __restrict__ msq) {
    __shared__ float rs[256], rq[256];
    int t = threadIdx.x;
    int col = t & 63;
    int row0 = blockIdx.x * 4 + (t >> 6);
    int rstride = gridDim.x * 4;
    float s = 0.f, q = 0.f;
    for (int n = row0; n < NN; n += rstride) {
        float v = m[(size_t)n * DD + col];
        s += v; q += v * v;
    }
    rs[t] = s; rq[t] = q;
    __syncthreads();
    if (t < 64) {
        s = rs[t] + rs[t + 64] + rs[t + 128] + rs[t + 192];
        q = rq[t] + rq[t + 64] + rq[t + 128] + rq[t + 192];
        unsafeAtomicAdd(&msum[t], s);
        unsafeAtomicAdd(&msq[t], q);
    }
}

// ---------------- finalize BN(m) coeffs; zero edge-stats for next layer ----------------
__global__ void fin_n_k(float* __restrict__ stats,
                        const float* __restrict__ gn, const float* __restrict__ bbn,
                        float* __restrict__ coeffN) {
    int j = threadIdx.x; // 64
    const float invN = 1.f / (float)NN;
    float mu = stats[256 + j] * invN;
    float var = stats[320 + j] * invN - mu * mu;
    float s = gn[j] * rsqrtf(var + 1e-5f);
    coeffN[j] = s;
    coeffN[64 + j] = bbn[j] - mu * s;
    stats[j] = 0.f;
    stats[64 + j] = 0.f;
    stats[128 + j] = 0.f;
    stats[192 + j] = 0.f;
}

// ---------------- h = sp(h + bn(m)) (fp32 + bf16 copy) ----------------
__global__ void h_update_k(float* __restrict__ h, unsigned short* __restrict__ hb,
                           const float* __restrict__ m,
                           const float* __restrict__ coeffN) {
    int i = blockIdx.x * 256 + threadIdx.x;
    if (i >= NN * DD) return;
    int j = i & 63;
    float v = h[i] + m[i] * coeffN[j] + coeffN[64 + j];
    v = sp_(v);
    h[i] = v;
    hb[i] = f2b(v);
}

// ---------------- pooling ----------------
__global__ void pool_k(const float* __restrict__ h, const int* __restrict__ gid,
                       float* __restrict__ pool) {
    int i = blockIdx.x * 256 + threadIdx.x;
    if (i >= NN * DD) return;
    int n = i >> 6;
    unsafeAtomicAdd(&pool[(size_t)gid[n] * DD + (i & 63)], h[i]);
}

__global__ void cnt_graph_k(const int* __restrict__ gid, float* __restrict__ pcnt) {
    int n = blockIdx.x * 256 + threadIdx.x;
    if (n < NN) unsafeAtomicAdd(&pcnt[gid[n]], 1.f);
}

// ---------------- head: sp, fc+sp, sp, out ----------------
__global__ __launch_bounds__(128) void head_k(const float* __restrict__ pool,
                                              const float* __restrict__ pcnt,
                                              const float* __restrict__ fcW,
                                              const float* __restrict__ fcb,
                                              const float* __restrict__ oW,
                                              const float* __restrict__ ob,
                                              float* __restrict__ out) {
    int g = blockIdx.x;
    int t = threadIdx.x; // 128
    __shared__ float feats[DD];
    __shared__ float red[FF];
    if (t < DD) {
        float c = fmaxf(pcnt[g], 1.f);
        feats[t] = sp_(pool[(size_t)g * DD + t] / c);
    }
    __syncthreads();
    float a = fcb[t];
#pragma unroll 1
    for (int j = 0; j < DD; ++j) a += feats[j] * fcW[j * FF + t];
    float y = sp_(sp_(a));
    red[t] = y * oW[t];
    __syncthreads();
    for (int s2 = 64; s2 >= 1; s2 >>= 1) {
        if (t < s2) red[t] += red[t + s2];
        __syncthreads();
    }
    if (t == 0) out[g] = red[0] + ob[0];
}

extern "C" void kernel_launch(void* const* d_in, const int* in_sizes, int n_in,
                              void* d_out, int out_size, void* d_ws, size_t ws_size,
                              hipStream_t stream) {
    const float* af   = (const float*)d_in[0];
    const float* bond = (const float*)d_in[1];
    const int*   src  = (const int*)d_in[2];
    const int*   dst  = (const int*)d_in[3];
    const int*   gid  = (const int*)d_in[4];
    const float* embW = (const float*)d_in[5];
    const float* embB = (const float*)d_in[6];
    const float* Wi   = (const float*)d_in[7];
    const float* gi   = (const float*)d_in[9];
    const float* bbi  = (const float*)d_in[10];
    const float* Wu   = (const float*)d_in[11];
    const float* gu   = (const float*)d_in[13];
    const float* bbu  = (const float*)d_in[14];
    const float* gn   = (const float*)d_in[15];
    const float* bbn  = (const float*)d_in[16];
    const float* fcW  = (const float*)d_in[17];
    const float* fcb  = (const float*)d_in[18];
    const float* oW   = (const float*)d_in[19];
    const float* ob   = (const float*)d_in[20];
    float* out = (float*)d_out;

    char* ws = (char*)d_ws;
    size_t off = 0;
    auto take = [&](size_t bytes) {
        size_t o = off;
        off += (bytes + 255) & ~(size_t)255;
        return o;
    };
    float* h     = (float*)(ws + take((size_t)NN * DD * 4));
    float* m     = (float*)(ws + take((size_t)NN * DD * 4));
    float* stats = (float*)(ws + take(512 * 4)); // [sumI,sqI,sumU,sqU | msum,msq]
    float* coeff = (float*)(ws + take(512 * 4)); // [sI,tI,sU,tU | sN,tN]
    float* pool  = (float*)(ws + take((size_t)NG * DD * 4)); // 32768 B
    float* pcnt  = (float*)(ws + take((size_t)NG * 4));      // 512 B padded
    int* ecount  = (int*)(ws + take((size_t)NN * 4));
    int* eoff    = (int*)(ws + take((size_t)(NN + 1) * 4));
    int* ecur    = (int*)(ws + take((size_t)NN * 4));
    int* elist   = (int*)(ws + take((size_t)NE * 4));
    int* ssrc    = (int*)(ws + take((size_t)NE * 4));
    int* sdst    = (int*)(ws + take((size_t)NE * 4));
    unsigned short* hb   = (unsigned short*)(ws + take((size_t)NN * DD * 2));
    unsigned short* rbfs = (unsigned short*)(ws + take((size_t)NE * 32 * 2));
    unsigned short* Wf   = (unsigned short*)(ws + take((size_t)6 * 10240 * 2));

    // zero: pool (32768) + pcnt (512 incl pad) + ecount (80000) — contiguous
    hipMemsetAsync((void*)pool, 0, 32768 + 512 + (size_t)NN * 4, stream);
    hipMemsetAsync((void*)stats, 0, 384 * 4, stream);

    prep_wf_k<<<6, 256, 0, stream>>>(Wi, Wu, Wf);
    embed_k<<<(NN + 255) / 256, 256, 0, stream>>>(af, embW, embB, h, hb);

    cnt_edges_k<<<(NE + 255) / 256, 256, 0, stream>>>(dst, ecount);
    csr_scan_k<<<1, 1024, 0, stream>>>(ecount, eoff, ecur);
    fill_edges_k<<<(NE + 255) / 256, 256, 0, stream>>>(src, dst, ecur, elist, ssrc, sdst);
    rbfs_k<<<(NE + 255) / 256, 256, 0, stream>>>(bond, elist, rbfs);

    for (int l = 0; l < 3; ++l) {
        const unsigned short* Wfl = Wf + (size_t)l * 2 * 10240;
        hipMemsetAsync((void*)m, 0, (size_t)NN * DD * 4, stream);
        edge_stats_k<<<1024, 256, 0, stream>>>(hb, rbfs, Wfl, ssrc, sdst, stats);
        fin_iu_k<<<1, 64, 0, stream>>>(stats, gi + l * DD, bbi + l * DD, gu + l * DD, bbu + l * DD,
                                       coeff);
        edge_apply_k<<<1024, 256, 0, stream>>>(hb, rbfs, Wfl, ssrc, sdst, coeff, m);
        m_stats_k<<<128, 256, 0, stream>>>(m, stats + 256, stats + 320);
        fin_n_k<<<1, 64, 0, stream>>>(stats, gn + l * DD, bbn + l * DD, coeff + 256);
        h_update_k<<<(NN * DD + 255) / 256, 256, 0, stream>>>(h, hb, m, coeff + 256);
    }

    pool_k<<<(NN * DD + 255) / 256, 256, 0, stream>>>(h, gid, pool);
    cnt_graph_k<<<(NN + 255) / 256, 256, 0, stream>>>(gid, pcnt);
    head_k<<<NG, 128, 0, stream>>>(pool, pcnt, fcW, fcb, oW, ob, out);
}

// Round 5
// 1072.151 us; speedup vs baseline: 1.3034x; 1.3034x over previous
//
#include <hip/hip_runtime.h>
#include <hip/hip_bf16.h>
#include <math.h>

#define NN 20000
#define NE 320000
#define NG 128
#define DD 64
#define FA 92
#define FF 128
#define NT (NE / 16)          // 16-edge MFMA tiles
#define GAMMA 3.875f          // 31/8
#define CEN (8.0f / 31.0f)    // center spacing

typedef __attribute__((ext_vector_type(8))) short bf16x8;
typedef __attribute__((ext_vector_type(4))) float f32x4;

// stats layout (floats): [0]=qI, [64]=qU, [128]=msum, [192]=msq, [256]=zsumS, [320]=zsumD, [384]=zsumR(32)

__device__ __forceinline__ float sp_(float x) {
    return fmaxf(x, 0.f) + __logf(1.f + __expf(-fabsf(x)));
}
__device__ __forceinline__ float sig_(float x) {
    return 1.f / (1.f + __expf(-x));
}
__device__ __forceinline__ unsigned short f2b(float x) {
    __hip_bfloat16 b = __float2bfloat16(x);
    return *reinterpret_cast<unsigned short*>(&b);
}
__device__ __forceinline__ float b2f(unsigned short u) {
    return __uint_as_float((unsigned)u << 16);
}

// ---------------- embedding: h = af @ emb_W + emb_b (fp32 + bf16 copy) ----------------
__global__ __launch_bounds__(256) void embed_k(const float* __restrict__ af,
                                               const float* __restrict__ W,
                                               const float* __restrict__ b,
                                               float* __restrict__ h,
                                               unsigned short* __restrict__ hb) {
    __shared__ float Ws[FA * DD];
    for (int i = threadIdx.x * 4; i < FA * DD; i += 256 * 4)
        *(float4*)&Ws[i] = *(const float4*)&W[i];
    __syncthreads();
    int n = blockIdx.x * 256 + threadIdx.x;
    if (n >= NN) return;
    float acc[DD];
#pragma unroll
    for (int j = 0; j < DD; ++j) acc[j] = b[j];
    const float* row = af + (size_t)n * FA;
#pragma unroll 1
    for (int k4 = 0; k4 < FA / 4; ++k4) {
        float4 z = *(const float4*)(row + k4 * 4);
#pragma unroll
        for (int kk = 0; kk < 4; ++kk) {
            float a = ((const float*)&z)[kk];
            const float* wr = &Ws[(k4 * 4 + kk) * DD];
#pragma unroll
            for (int j = 0; j < DD; j += 4) {
                float4 w = *(const float4*)(wr + j);
                acc[j + 0] += a * w.x; acc[j + 1] += a * w.y;
                acc[j + 2] += a * w.z; acc[j + 3] += a * w.w;
            }
        }
    }
    float* o = h + (size_t)n * DD;
    unsigned short* ob = hb + (size_t)n * DD;
#pragma unroll
    for (int j = 0; j < DD; j += 4) {
        float4 v; v.x = acc[j]; v.y = acc[j + 1]; v.z = acc[j + 2]; v.w = acc[j + 3];
        *(float4*)(o + j) = v;
    }
#pragma unroll
    for (int j = 0; j < DD; ++j) ob[j] = f2b(acc[j]);
}

// ---------------- weight fragment prep: element = W[kt*32+8c+i][nf*16+r] ----------------
__global__ void prep_wf_k(const float* __restrict__ Wi, const float* __restrict__ Wu,
                          unsigned short* __restrict__ Wf) {
    int b = blockIdx.x;          // 0..5 : layer*2 + gate
    int l = b >> 1, g = b & 1;
    const float* W = (g ? Wu : Wi) + (size_t)l * 160 * DD;
    for (int f = threadIdx.x; f < 10240; f += 256) {
        int i = f & 7;
        int lane = (f >> 3) & 63;
        int nf = (f >> 9) & 3;
        int kt = f >> 11;
        int k = kt * 32 + 8 * (lane >> 4) + i;
        int col = nf * 16 + (lane & 15);
        Wf[(size_t)b * 10240 + f] = f2b(W[k * DD + col]);
    }
}

// ---------------- CSR build (sorted-by-dst edge order) ----------------
__global__ void cnt_edges_k(const int* __restrict__ src, const int* __restrict__ dst,
                            int* __restrict__ icnt, int* __restrict__ ocnt) {
    int e = blockIdx.x * 256 + threadIdx.x;
    if (e < NE) {
        atomicAdd(&icnt[dst[e]], 1);
        atomicAdd(&ocnt[src[e]], 1);
    }
}

__global__ __launch_bounds__(1024) void csr_scan_k(const int* __restrict__ cnt,
                                                   int* __restrict__ off,
                                                   int* __restrict__ cur) {
    __shared__ int part[1024];
    int t = threadIdx.x;
    int base = t * 20;
    int s = 0;
    for (int i = 0; i < 20; ++i) { int idx = base + i; if (idx < NN) s += cnt[idx]; }
    part[t] = s;
    __syncthreads();
    for (int ofs = 1; ofs < 1024; ofs <<= 1) {
        int v = (t >= ofs) ? part[t - ofs] : 0;
        __syncthreads();
        part[t] += v;
        __syncthreads();
    }
    int run = (t == 0) ? 0 : part[t - 1];
    for (int i = 0; i < 20; ++i) {
        int idx = base + i;
        if (idx < NN) { off[idx] = run; cur[idx] = run; run += cnt[idx]; }
    }
    if (t == 1023) off[NN] = run;
}

__global__ void fill_edges_k(const int* __restrict__ src, const int* __restrict__ dst,
                             const float* __restrict__ bond,
                             int* __restrict__ cur, int* __restrict__ ssrc,
                             int* __restrict__ sdst, float* __restrict__ bond_s) {
    int e = blockIdx.x * 256 + threadIdx.x;
    if (e < NE) {
        int d = dst[e];
        int p = atomicAdd(&cur[d], 1);
        ssrc[p] = src[e];
        sdst[p] = d;
        bond_s[p] = bond[e];
    }
}

// ---------------- one-time: column sum of bf16-rounded rbf over all edges ----------------
__global__ void rbfsum_k(const float* __restrict__ bond, float* __restrict__ zr) {
    int t = blockIdx.x * 256 + threadIdx.x;
    int col = t & 31;
    int idx = t >> 5;
    int stride = (gridDim.x * 256) >> 5;
    float cen = (float)col * CEN;
    float a = 0.f;
    for (int e = idx; e < NE; e += stride) {
        float u = bond[e] - cen;
        a += b2f(f2b(__expf(-GAMMA * u * u)));
    }
    unsafeAtomicAdd(&zr[col], a);
}

// ---------------- per layer: degree-weighted column sums of hb ----------------
__global__ __launch_bounds__(256) void zsum_node_k(const unsigned short* __restrict__ hb,
                                                   const int* __restrict__ ocnt,
                                                   const int* __restrict__ icnt,
                                                   float* __restrict__ zS,
                                                   float* __restrict__ zD) {
    int t = blockIdx.x * 256 + threadIdx.x;
    int col = t & 63;
    int n0 = t >> 6;
    int nstride = (gridDim.x * 256) >> 6;
    float aS = 0.f, aD = 0.f;
    for (int n = n0; n < NN; n += nstride) {
        float v = b2f(hb[(size_t)n * DD + col]);
        aS += (float)ocnt[n] * v;
        aD += (float)icnt[n] * v;
    }
    unsafeAtomicAdd(&zS[col], aS);
    unsafeAtomicAdd(&zD[col], aD);
}

// ---------------- gather-GEMM (swapped operands): pre (bf16, edge-major) + col sumsq ----------------
__global__ __launch_bounds__(256) void edge_pre_k(const unsigned short* __restrict__ hb,
                                                  const float* __restrict__ bond_s,
                                                  const unsigned short* __restrict__ Wf,
                                                  const int* __restrict__ ssrc,
                                                  const int* __restrict__ sdst,
                                                  unsigned short* __restrict__ preIb,
                                                  unsigned short* __restrict__ preUb,
                                                  float* __restrict__ qstat) {
    __shared__ bf16x8 WfS[2560]; // 40 KB : [gate][kt][nf][lane]
    {
        const bf16x8* Wf8 = (const bf16x8*)Wf;
        for (int i = threadIdx.x; i < 2560; i += 256) WfS[i] = Wf8[i];
    }
    __syncthreads();

    const int lane = threadIdx.x & 63;
    const int r = lane & 15;   // edge-within-tile (D col with swapped operands)
    const int c = lane >> 4;   // k-chunk / D row group
    const int wid = (blockIdx.x * 256 + threadIdx.x) >> 6;
    const int nwaves = (gridDim.x * 256) >> 6;

    float qI[16], qU[16];
#pragma unroll
    for (int s = 0; s < 16; ++s) { qI[s] = 0.f; qU[s] = 0.f; }

    int tile = wid;
    int es = 0, ed = 0; float bd = 0.f;
    if (tile < NT) { es = ssrc[tile * 16 + r]; ed = sdst[tile * 16 + r]; bd = bond_s[tile * 16 + r]; }

    while (tile < NT) {
        const int e = tile * 16 + r;
        bf16x8 a0 = *(const bf16x8*)(hb + (size_t)es * DD + c * 8);
        bf16x8 a1 = *(const bf16x8*)(hb + (size_t)es * DD + 32 + c * 8);
        bf16x8 a2 = *(const bf16x8*)(hb + (size_t)ed * DD + c * 8);
        bf16x8 a3 = *(const bf16x8*)(hb + (size_t)ed * DD + 32 + c * 8);
        bf16x8 a4;
#pragma unroll
        for (int i = 0; i < 8; ++i) {
            float cen = (float)(8 * c + i) * CEN;
            float u = bd - cen;
            a4[i] = (short)f2b(__expf(-GAMMA * u * u));
        }

        int ntile = tile + nwaves;
        int es_n = 0, ed_n = 0; float bd_n = 0.f;
        if (ntile < NT) { es_n = ssrc[ntile * 16 + r]; ed_n = sdst[ntile * 16 + r]; bd_n = bond_s[ntile * 16 + r]; }

        f32x4 accI[4], accU[4];
#pragma unroll
        for (int nf = 0; nf < 4; ++nf) {
            f32x4 z4 = {0.f, 0.f, 0.f, 0.f};
            accI[nf] = z4; accU[nf] = z4;
        }
#pragma unroll
        for (int kt = 0; kt < 5; ++kt) {
            bf16x8 a = (kt == 0) ? a0 : (kt == 1) ? a1 : (kt == 2) ? a2 : (kt == 3) ? a3 : a4;
#pragma unroll
            for (int nf = 0; nf < 4; ++nf) {
                // swapped: A = W^T fragment, B = z fragment  =>  D[outcol][edge]
                accI[nf] = __builtin_amdgcn_mfma_f32_16x16x32_bf16(WfS[(kt * 4 + nf) * 64 + lane], a, accI[nf], 0, 0, 0);
                accU[nf] = __builtin_amdgcn_mfma_f32_16x16x32_bf16(WfS[1280 + (kt * 4 + nf) * 64 + lane], a, accU[nf], 0, 0, 0);
            }
        }
        // lane holds edge e, cols nf*16 + c*4 + j  -> contiguous 8B stores
        unsigned short* pI = preIb + (size_t)e * DD + c * 4;
        unsigned short* pU = preUb + (size_t)e * DD + c * 4;
#pragma unroll
        for (int nf = 0; nf < 4; ++nf) {
            ushort4 oI, oU;
            oI.x = f2b(accI[nf][0]); oI.y = f2b(accI[nf][1]);
            oI.z = f2b(accI[nf][2]); oI.w = f2b(accI[nf][3]);
            oU.x = f2b(accU[nf][0]); oU.y = f2b(accU[nf][1]);
            oU.z = f2b(accU[nf][2]); oU.w = f2b(accU[nf][3]);
            *(ushort4*)(pI + nf * 16) = oI;
            *(ushort4*)(pU + nf * 16) = oU;
#pragma unroll
            for (int j = 0; j < 4; ++j) {
                qI[nf * 4 + j] += accI[nf][j] * accI[nf][j];
                qU[nf * 4 + j] += accU[nf][j] * accU[nf][j];
            }
        }
        tile = ntile; es = es_n; ed = ed_n; bd = bd_n;
    }

    // reduce sumsq over the 16 r-lanes; one atomic pair per lane
    float vq = 0.f, vu = 0.f;
#pragma unroll
    for (int s = 0; s < 16; ++s) {
        float a = qI[s];
        a += __shfl_xor(a, 1, 64); a += __shfl_xor(a, 2, 64);
        a += __shfl_xor(a, 4, 64); a += __shfl_xor(a, 8, 64);
        float b = qU[s];
        b += __shfl_xor(b, 1, 64); b += __shfl_xor(b, 2, 64);
        b += __shfl_xor(b, 4, 64); b += __shfl_xor(b, 8, 64);
        if (r == s) { vq = a; vu = b; }
    }
    int col = (r >> 2) * 16 + c * 4 + (r & 3);
    unsafeAtomicAdd(&qstat[col], vq);
    unsafeAtomicAdd(&qstat[64 + col], vu);
}

// ---------------- BN coeffs for gate/update: mean via linearity, var via sumsq ----------------
__global__ void fin_iu_k(float* __restrict__ stats,
                         const unsigned short* __restrict__ Wf, // layer base [2][10240]
                         const float* __restrict__ gi, const float* __restrict__ bbi,
                         const float* __restrict__ gu, const float* __restrict__ bbu,
                         float* __restrict__ coeff) {
    int j = threadIdx.x; // 64 = out col
    int nf = j >> 4, rr = j & 15;
    float muI = 0.f, muU = 0.f;
    for (int k = 0; k < 160; ++k) {
        float zs = (k < 64) ? stats[256 + k] : (k < 128) ? stats[320 + k - 64] : stats[384 + k - 128];
        int kt = k >> 5, rem = k & 31, cc = rem >> 3, ii = rem & 7;
        int f = kt * 2048 + nf * 512 + (cc * 16 + rr) * 8 + ii;
        muI += zs * b2f(Wf[f]);
        muU += zs * b2f(Wf[10240 + f]);
    }
    const float invE = 1.f / (float)NE;
    muI *= invE; muU *= invE;
    float varI = stats[j] * invE - muI * muI;
    float sI = gi[j] * rsqrtf(varI + 1e-5f);
    coeff[j] = sI;
    coeff[64 + j] = bbi[j] - muI * sI;
    float varU = stats[64 + j] * invE - muU * muU;
    float sU = gu[j] * rsqrtf(varU + 1e-5f);
    coeff[128 + j] = sU;
    coeff[192 + j] = bbu[j] - muU * sU;
    stats[128 + j] = 0.f;  // msum
    stats[192 + j] = 0.f;  // msq
}

// ---------------- node-parallel apply: BN + sig*softplus + exact segment sum (no atomics) ----------------
__global__ __launch_bounds__(256) void apply_node_k(const unsigned short* __restrict__ preIb,
                                                    const unsigned short* __restrict__ preUb,
                                                    const int* __restrict__ eoff,
                                                    const float* __restrict__ coeff,
                                                    float* __restrict__ m) {
    int t = blockIdx.x * 256 + threadIdx.x; // NN*8 threads
    int chunk = t & 7;
    int n = t >> 3;
    if (n >= NN) return;
    float sIv[8], tIv[8], sUv[8], tUv[8];
#pragma unroll
    for (int q = 0; q < 8; ++q) {
        int col = chunk * 8 + q;
        sIv[q] = coeff[col];       tIv[q] = coeff[64 + col];
        sUv[q] = coeff[128 + col]; tUv[q] = coeff[192 + col];
    }
    int b = eoff[n], e = eoff[n + 1];
    float acc[8];
#pragma unroll
    for (int q = 0; q < 8; ++q) acc[q] = 0.f;
    for (int p = b; p < e; ++p) {
        bf16x8 vi = *(const bf16x8*)(preIb + (size_t)p * DD + chunk * 8);
        bf16x8 vu = *(const bf16x8*)(preUb + (size_t)p * DD + chunk * 8);
#pragma unroll
        for (int q = 0; q < 8; ++q) {
            float xi = b2f((unsigned short)vi[q]) * sIv[q] + tIv[q];
            float xu = b2f((unsigned short)vu[q]) * sUv[q] + tUv[q];
            acc[q] += sig_(xi) * sp_(xu);
        }
    }
    float* mp = m + (size_t)n * DD + chunk * 8;
    float4 v0, v1;
    v0.x = acc[0]; v0.y = acc[1]; v0.z = acc[2]; v0.w = acc[3];
    v1.x = acc[4]; v1.y = acc[5]; v1.z = acc[6]; v1.w = acc[7];
    *(float4*)mp = v0;
    *(float4*)(mp + 4) = v1;
}

// ---------------- m column stats ----------------
__global__ __launch_bounds__(256) void m_stats_k(const float* __restrict__ m,
                                                 float* __restrict__ msum,
                                                 float* __restrict__ msq) {
    __shared__ float rs[256], rq[256];
    int t = threadIdx.x;
    int col = t & 63;
    int row0 = blockIdx.x * 4 + (t >> 6);
    int rstride = gridDim.x * 4;
    float s = 0.f, q = 0.f;
    for (int n = row0; n < NN; n += rstride) {
        float v = m[(size_t)n * DD + col];
        s += v; q += v * v;
    }
    rs[t] = s; rq[t] = q;
    __syncthreads();
    if (t < 64) {
        s = rs[t] + rs[t + 64] + rs[t + 128] + rs[t + 192];
        q = rq[t] + rq[t + 64] + rq[t + 128] + rq[t + 192];
        unsafeAtomicAdd(&msum[t], s);
        unsafeAtomicAdd(&msq[t], q);
    }
}

// ---------------- finalize BN(m); zero next layer's accumulators ----------------
__global__ void fin_n_k(float* __restrict__ stats,
                        const float* __restrict__ gn, const float* __restrict__ bbn,
                        float* __restrict__ coeffN) {
    int j = threadIdx.x; // 64
    const float invN = 1.f / (float)NN;
    float mu = stats[128 + j] * invN;
    float var = stats[192 + j] * invN - mu * mu;
    float s = gn[j] * rsqrtf(var + 1e-5f);
    coeffN[j] = s;
    coeffN[64 + j] = bbn[j] - mu * s;
    stats[j] = 0.f;        // qI
    stats[64 + j] = 0.f;   // qU
    stats[256 + j] = 0.f;  // zsumS
    stats[320 + j] = 0.f;  // zsumD
}

// ---------------- h = sp(h + bn(m)) ----------------
__global__ void h_update_k(float* __restrict__ h, unsigned short* __restrict__ hb,
                           const float* __restrict__ m,
                           const float* __restrict__ coeffN) {
    int i = blockIdx.x * 256 + threadIdx.x;
    if (i >= NN * DD) return;
    int j = i & 63;
    float v = h[i] + m[i] * coeffN[j] + coeffN[64 + j];
    v = sp_(v);
    h[i] = v;
    hb[i] = f2b(v);
}

// ---------------- pooling ----------------
__global__ void pool_k(const float* __restrict__ h, const int* __restrict__ gid,
                       float* __restrict__ pool) {
    int i = blockIdx.x * 256 + threadIdx.x;
    if (i >= NN * DD) return;
    int n = i >> 6;
    unsafeAtomicAdd(&pool[(size_t)gid[n] * DD + (i & 63)], h[i]);
}

__global__ void cnt_graph_k(const int* __restrict__ gid, float* __restrict__ pcnt) {
    int n = blockIdx.x * 256 + threadIdx.x;
    if (n < NN) unsafeAtomicAdd(&pcnt[gid[n]], 1.f);
}

// ---------------- head ----------------
__global__ __launch_bounds__(128) void head_k(const float* __restrict__ pool,
                                              const float* __restrict__ pcnt,
                                              const float* __restrict__ fcW,
                                              const float* __restrict__ fcb,
                                              const float* __restrict__ oW,
                                              const float* __restrict__ ob,
                                              float* __restrict__ out) {
    int g = blockIdx.x;
    int t = threadIdx.x; // 128
    __shared__ float feats[DD];
    __shared__ float red[FF];
    if (t < DD) {
        float c = fmaxf(pcnt[g], 1.f);
        feats[t] = sp_(pool[(size_t)g * DD + t] / c);
    }
    __syncthreads();
    float a = fcb[t];
#pragma unroll 1
    for (int j = 0; j < DD; ++j) a += feats[j] * fcW[j * FF + t];
    float y = sp_(sp_(a));
    red[t] = y * oW[t];
    __syncthreads();
    for (int s2 = 64; s2 >= 1; s2 >>= 1) {
        if (t < s2) red[t] += red[t + s2];
        __syncthreads();
    }
    if (t == 0) out[g] = red[0] + ob[0];
}

extern "C" void kernel_launch(void* const* d_in, const int* in_sizes, int n_in,
                              void* d_out, int out_size, void* d_ws, size_t ws_size,
                              hipStream_t stream) {
    const float* af   = (const float*)d_in[0];
    const float* bond = (const float*)d_in[1];
    const int*   src  = (const int*)d_in[2];
    const int*   dst  = (const int*)d_in[3];
    const int*   gid  = (const int*)d_in[4];
    const float* embW = (const float*)d_in[5];
    const float* embB = (const float*)d_in[6];
    const float* Wi   = (const float*)d_in[7];
    const float* gi   = (const float*)d_in[9];
    const float* bbi  = (const float*)d_in[10];
    const float* Wu   = (const float*)d_in[11];
    const float* gu   = (const float*)d_in[13];
    const float* bbu  = (const float*)d_in[14];
    const float* gn   = (const float*)d_in[15];
    const float* bbn  = (const float*)d_in[16];
    const float* fcW  = (const float*)d_in[17];
    const float* fcb  = (const float*)d_in[18];
    const float* oW   = (const float*)d_in[19];
    const float* ob   = (const float*)d_in[20];
    float* out = (float*)d_out;

    char* ws = (char*)d_ws;
    size_t off = 0;
    auto take = [&](size_t bytes) {
        size_t o = off;
        off += (bytes + 255) & ~(size_t)255;
        return o;
    };
    float* h     = (float*)(ws + take((size_t)NN * DD * 4));
    float* m     = (float*)(ws + take((size_t)NN * DD * 4));
    float* stats = (float*)(ws + take(512 * 4));
    float* coeff = (float*)(ws + take(512 * 4)); // [sI,tI,sU,tU | sN,tN]
    float* pool  = (float*)(ws + take((size_t)NG * DD * 4)); // 32768 B
    float* pcnt  = (float*)(ws + take((size_t)NG * 4));      // 512 B padded
    int* ecount  = (int*)(ws + take((size_t)NN * 4));        // indeg
    int* ocount  = (int*)(ws + take((size_t)NN * 4));        // outdeg (contiguous after ecount)
    int* eoff    = (int*)(ws + take((size_t)(NN + 1) * 4));
    int* ecur    = (int*)(ws + take((size_t)NN * 4));
    int* ssrc    = (int*)(ws + take((size_t)NE * 4));
    int* sdst    = (int*)(ws + take((size_t)NE * 4));
    float* bond_s = (float*)(ws + take((size_t)NE * 4));
    unsigned short* hb    = (unsigned short*)(ws + take((size_t)NN * DD * 2));
    unsigned short* preIb = (unsigned short*)(ws + take((size_t)NE * DD * 2));
    unsigned short* preUb = (unsigned short*)(ws + take((size_t)NE * DD * 2));
    unsigned short* Wf    = (unsigned short*)(ws + take((size_t)6 * 10240 * 2));

    // zero: pool+pcnt (contiguous), ecount+ocount (contiguous), stats
    hipMemsetAsync((void*)pool, 0, 32768 + 512, stream);
    hipMemsetAsync((void*)ecount, 0, 2 * (((size_t)NN * 4 + 255) & ~(size_t)255), stream);
    hipMemsetAsync((void*)stats, 0, 512 * 4, stream);

    prep_wf_k<<<6, 256, 0, stream>>>(Wi, Wu, Wf);
    embed_k<<<(NN + 255) / 256, 256, 0, stream>>>(af, embW, embB, h, hb);

    cnt_edges_k<<<(NE + 255) / 256, 256, 0, stream>>>(src, dst, ecount, ocount);
    csr_scan_k<<<1, 1024, 0, stream>>>(ecount, eoff, ecur);
    fill_edges_k<<<(NE + 255) / 256, 256, 0, stream>>>(src, dst, bond, ecur, ssrc, sdst, bond_s);
    rbfsum_k<<<256, 256, 0, stream>>>(bond, stats + 384);

    for (int l = 0; l < 3; ++l) {
        const unsigned short* Wfl = Wf + (size_t)l * 2 * 10240;
        zsum_node_k<<<128, 256, 0, stream>>>(hb, ocount, ecount, stats + 256, stats + 320);
        edge_pre_k<<<1250, 256, 0, stream>>>(hb, bond_s, Wfl, ssrc, sdst, preIb, preUb, stats);
        fin_iu_k<<<1, 64, 0, stream>>>(stats, Wfl, gi + l * DD, bbi + l * DD,
                                       gu + l * DD, bbu + l * DD, coeff);
        apply_node_k<<<NN * 8 / 256, 256, 0, stream>>>(preIb, preUb, eoff, coeff, m);
        m_stats_k<<<128, 256, 0, stream>>>(m, stats + 128, stats + 192);
        fin_n_k<<<1, 64, 0, stream>>>(stats, gn + l * DD, bbn + l * DD, coeff + 256);
        h_update_k<<<(NN * DD + 255) / 256, 256, 0, stream>>>(h, hb, m, coeff + 256);
    }

    pool_k<<<(NN * DD + 255) / 256, 256, 0, stream>>>(h, gid, pool);
    cnt_graph_k<<<(NN + 255) / 256, 256, 0, stream>>>(gid, pcnt);
    head_k<<<NG, 128, 0, stream>>>(pool, pcnt, fcW, fcb, oW, ob, out);
}

// Round 6
// 891.317 us; speedup vs baseline: 1.5678x; 1.2029x over previous
//
#include <hip/hip_runtime.h>
#include <hip/hip_bf16.h>
#include <math.h>

#define NN 20000
#define NE 320000
#define NG 128
#define DD 64
#define FA 92
#define FF 128
#define NT (NE / 16)          // 16-edge MFMA tiles
#define NBLK 2500             // blocks per gate in edge_pre2
#define GAMMA 3.875f          // 31/8
#define CEN (8.0f / 31.0f)    // center spacing

typedef __attribute__((ext_vector_type(8))) short bf16x8;
typedef __attribute__((ext_vector_type(4))) float f32x4;

// stats layout (floats): [0]=qI, [64]=qU, [128]=msum, [192]=msq, [256]=zsumS, [320]=zsumD, [384]=zsumR(32)

__device__ __forceinline__ float sp_(float x) {
    return fmaxf(x, 0.f) + __logf(1.f + __expf(-fabsf(x)));
}
__device__ __forceinline__ float sig_(float x) {
    return 1.f / (1.f + __expf(-x));
}
__device__ __forceinline__ unsigned short f2b(float x) {
    __hip_bfloat16 b = __float2bfloat16(x);
    return *reinterpret_cast<unsigned short*>(&b);
}
__device__ __forceinline__ float b2f(unsigned short u) {
    return __uint_as_float((unsigned)u << 16);
}

// ---------------- embedding: h = af @ emb_W + emb_b (fp32 + bf16 copy) ----------------
__global__ __launch_bounds__(256) void embed_k(const float* __restrict__ af,
                                               const float* __restrict__ W,
                                               const float* __restrict__ b,
                                               float* __restrict__ h,
                                               unsigned short* __restrict__ hb) {
    __shared__ float Ws[FA * DD];
    for (int i = threadIdx.x * 4; i < FA * DD; i += 256 * 4)
        *(float4*)&Ws[i] = *(const float4*)&W[i];
    __syncthreads();
    int n = blockIdx.x * 256 + threadIdx.x;
    if (n >= NN) return;
    float acc[DD];
#pragma unroll
    for (int j = 0; j < DD; ++j) acc[j] = b[j];
    const float* row = af + (size_t)n * FA;
#pragma unroll 1
    for (int k4 = 0; k4 < FA / 4; ++k4) {
        float4 z = *(const float4*)(row + k4 * 4);
#pragma unroll
        for (int kk = 0; kk < 4; ++kk) {
            float a = ((const float*)&z)[kk];
            const float* wr = &Ws[(k4 * 4 + kk) * DD];
#pragma unroll
            for (int j = 0; j < DD; j += 4) {
                float4 w = *(const float4*)(wr + j);
                acc[j + 0] += a * w.x; acc[j + 1] += a * w.y;
                acc[j + 2] += a * w.z; acc[j + 3] += a * w.w;
            }
        }
    }
    float* o = h + (size_t)n * DD;
    unsigned short* ob = hb + (size_t)n * DD;
#pragma unroll
    for (int j = 0; j < DD; j += 4) {
        float4 v; v.x = acc[j]; v.y = acc[j + 1]; v.z = acc[j + 2]; v.w = acc[j + 3];
        *(float4*)(o + j) = v;
    }
#pragma unroll
    for (int j = 0; j < DD; ++j) ob[j] = f2b(acc[j]);
}

// ---------------- weight fragment prep: element = W[kt*32+8c+i][nf*16+r] ----------------
__global__ void prep_wf_k(const float* __restrict__ Wi, const float* __restrict__ Wu,
                          unsigned short* __restrict__ Wf) {
    int b = blockIdx.x;          // 0..5 : layer*2 + gate
    int l = b >> 1, g = b & 1;
    const float* W = (g ? Wu : Wi) + (size_t)l * 160 * DD;
    for (int f = threadIdx.x; f < 10240; f += 256) {
        int i = f & 7;
        int lane = (f >> 3) & 63;
        int nf = (f >> 9) & 3;
        int kt = f >> 11;
        int k = kt * 32 + 8 * (lane >> 4) + i;
        int col = nf * 16 + (lane & 15);
        Wf[(size_t)b * 10240 + f] = f2b(W[k * DD + col]);
    }
}

// ---------------- CSR build (sorted-by-dst edge order) ----------------
__global__ void cnt_edges_k(const int* __restrict__ src, const int* __restrict__ dst,
                            int* __restrict__ icnt, int* __restrict__ ocnt) {
    int e = blockIdx.x * 256 + threadIdx.x;
    if (e < NE) {
        atomicAdd(&icnt[dst[e]], 1);
        atomicAdd(&ocnt[src[e]], 1);
    }
}

__global__ __launch_bounds__(1024) void csr_scan_k(const int* __restrict__ cnt,
                                                   int* __restrict__ off,
                                                   int* __restrict__ cur) {
    __shared__ int part[1024];
    int t = threadIdx.x;
    int base = t * 20;
    int s = 0;
    for (int i = 0; i < 20; ++i) { int idx = base + i; if (idx < NN) s += cnt[idx]; }
    part[t] = s;
    __syncthreads();
    for (int ofs = 1; ofs < 1024; ofs <<= 1) {
        int v = (t >= ofs) ? part[t - ofs] : 0;
        __syncthreads();
        part[t] += v;
        __syncthreads();
    }
    int run = (t == 0) ? 0 : part[t - 1];
    for (int i = 0; i < 20; ++i) {
        int idx = base + i;
        if (idx < NN) { off[idx] = run; cur[idx] = run; run += cnt[idx]; }
    }
    if (t == 1023) off[NN] = run;
}

__global__ void fill_edges_k(const int* __restrict__ src, const int* __restrict__ dst,
                             const float* __restrict__ bond,
                             int* __restrict__ cur, int* __restrict__ ssrc,
                             int* __restrict__ sdst, float* __restrict__ bond_s) {
    int e = blockIdx.x * 256 + threadIdx.x;
    if (e < NE) {
        int d = dst[e];
        int p = atomicAdd(&cur[d], 1);
        ssrc[p] = src[e];
        sdst[p] = d;
        bond_s[p] = bond[e];
    }
}

// ---------------- one-time: column sum of bf16-rounded rbf over all edges ----------------
__global__ void rbfsum_k(const float* __restrict__ bond, float* __restrict__ zr) {
    int t = blockIdx.x * 256 + threadIdx.x;
    int col = t & 31;
    int idx = t >> 5;
    int stride = (gridDim.x * 256) >> 5;
    float cen = (float)col * CEN;
    float a = 0.f;
    for (int e = idx; e < NE; e += stride) {
        float u = bond[e] - cen;
        a += b2f(f2b(__expf(-GAMMA * u * u)));
    }
    // halve atomic count: lanes l and l+32 share col
    a += __shfl_xor(a, 32, 64);
    if ((t & 63) < 32) unsafeAtomicAdd(&zr[col], a);
}

// ---------------- per layer: degree-weighted column sums of hb ----------------
__global__ __launch_bounds__(256) void zsum_node_k(const unsigned short* __restrict__ hb,
                                                   const int* __restrict__ ocnt,
                                                   const int* __restrict__ icnt,
                                                   float* __restrict__ zS,
                                                   float* __restrict__ zD) {
    int t = blockIdx.x * 256 + threadIdx.x;
    int col = t & 63;
    int n0 = t >> 6;
    int nstride = (gridDim.x * 256) >> 6;
    float aS = 0.f, aD = 0.f;
    for (int n = n0; n < NN; n += nstride) {
        float v = b2f(hb[(size_t)n * DD + col]);
        aS += (float)ocnt[n] * v;
        aD += (float)icnt[n] * v;
    }
    unsafeAtomicAdd(&zS[col], aS);
    unsafeAtomicAdd(&zD[col], aD);
}

// ---------------- gather-GEMM, gate-split: pre (bf16, edge-major) + per-block sumsq partials ----------------
__global__ __launch_bounds__(256) void edge_pre2_k(const unsigned short* __restrict__ hb,
                                                   const float* __restrict__ bond_s,
                                                   const unsigned short* __restrict__ Wf, // layer base [2][10240]
                                                   const int* __restrict__ ssrc,
                                                   const int* __restrict__ sdst,
                                                   unsigned short* __restrict__ preIb,
                                                   unsigned short* __restrict__ preUb,
                                                   float* __restrict__ pq) {
    __shared__ bf16x8 WfS[1280];     // 20 KB : [kt][nf][lane] for this block's gate
    __shared__ float qred_s[4][64];  // 1 KB cross-wave sumsq reduce
    const int g = blockIdx.x & 1;
    const int bidx = blockIdx.x >> 1;       // 0..NBLK-1
    {
        const bf16x8* Wf8 = (const bf16x8*)Wf + (size_t)g * 1280;
        for (int i = threadIdx.x; i < 1280; i += 256) WfS[i] = Wf8[i];
    }
    __syncthreads();

    const int lane = threadIdx.x & 63;
    const int w = threadIdx.x >> 6;
    const int r = lane & 15;   // edge-within-tile (D col with swapped operands)
    const int c = lane >> 4;   // k-chunk / D row group
    unsigned short* pre = g ? preUb : preIb;

    float q[16];
#pragma unroll
    for (int s = 0; s < 16; ++s) q[s] = 0.f;

    int tile = bidx * 4 + w;   // waves-per-gate = NBLK*4 = 10000; exactly 2 tiles each
    int es = ssrc[tile * 16 + r];
    int ed = sdst[tile * 16 + r];
    float bd = bond_s[tile * 16 + r];

    while (tile < NT) {
        const int e = tile * 16 + r;
        bf16x8 a0 = *(const bf16x8*)(hb + (size_t)es * DD + c * 8);
        bf16x8 a1 = *(const bf16x8*)(hb + (size_t)es * DD + 32 + c * 8);
        bf16x8 a2 = *(const bf16x8*)(hb + (size_t)ed * DD + c * 8);
        bf16x8 a3 = *(const bf16x8*)(hb + (size_t)ed * DD + 32 + c * 8);
        bf16x8 a4;
#pragma unroll
        for (int i = 0; i < 8; ++i) {
            float cen = (float)(8 * c + i) * CEN;
            float u = bd - cen;
            a4[i] = (short)f2b(__expf(-GAMMA * u * u));
        }

        int ntile = tile + NBLK * 4;
        int es_n = 0, ed_n = 0; float bd_n = 0.f;
        if (ntile < NT) { es_n = ssrc[ntile * 16 + r]; ed_n = sdst[ntile * 16 + r]; bd_n = bond_s[ntile * 16 + r]; }

        f32x4 acc[4];
#pragma unroll
        for (int nf = 0; nf < 4; ++nf) {
            f32x4 z4 = {0.f, 0.f, 0.f, 0.f};
            acc[nf] = z4;
        }
#pragma unroll
        for (int kt = 0; kt < 5; ++kt) {
            bf16x8 a = (kt == 0) ? a0 : (kt == 1) ? a1 : (kt == 2) ? a2 : (kt == 3) ? a3 : a4;
#pragma unroll
            for (int nf = 0; nf < 4; ++nf) {
                // swapped operands: A = W^T fragment, B = z fragment  =>  D[outcol][edge]
                acc[nf] = __builtin_amdgcn_mfma_f32_16x16x32_bf16(WfS[(kt * 4 + nf) * 64 + lane], a, acc[nf], 0, 0, 0);
            }
        }
        unsigned short* p = pre + (size_t)e * DD + c * 4;
#pragma unroll
        for (int nf = 0; nf < 4; ++nf) {
            ushort4 o;
            o.x = f2b(acc[nf][0]); o.y = f2b(acc[nf][1]);
            o.z = f2b(acc[nf][2]); o.w = f2b(acc[nf][3]);
            *(ushort4*)(p + nf * 16) = o;
#pragma unroll
            for (int j = 0; j < 4; ++j)
                q[nf * 4 + j] += acc[nf][j] * acc[nf][j];
        }
        tile = ntile; es = es_n; ed = ed_n; bd = bd_n;
    }

    // reduce sumsq across the 16 r-lanes of each c-group
    float vq = 0.f;
#pragma unroll
    for (int s = 0; s < 16; ++s) {
        float a = q[s];
        a += __shfl_xor(a, 1, 64); a += __shfl_xor(a, 2, 64);
        a += __shfl_xor(a, 4, 64); a += __shfl_xor(a, 8, 64);
        if (r == s) vq = a;
    }
    int col = (r >> 2) * 16 + c * 4 + (r & 3);
    qred_s[w][col] = vq;
    __syncthreads();
    if (w == 0) {
        float s4 = qred_s[0][lane] + qred_s[1][lane] + qred_s[2][lane] + qred_s[3][lane];
        pq[((size_t)g * 64 + lane) * NBLK + bidx] = s4;  // no atomics
    }
}

// ---------------- reduce per-block sumsq partials -> stats[0..127] ----------------
__global__ __launch_bounds__(256) void qred_k(const float* __restrict__ pq,
                                              float* __restrict__ stats) {
    __shared__ float red[256];
    int row = blockIdx.x; // 0..127 : [qI cols | qU cols]
    float s = 0.f;
    for (int i = threadIdx.x; i < NBLK; i += 256) s += pq[(size_t)row * NBLK + i];
    red[threadIdx.x] = s;
    __syncthreads();
    for (int ofs = 128; ofs >= 1; ofs >>= 1) {
        if (threadIdx.x < ofs) red[threadIdx.x] += red[threadIdx.x + ofs];
        __syncthreads();
    }
    if (threadIdx.x == 0) stats[row] = red[0];
}

// ---------------- BN coeffs for gate/update: mean via linearity, var via sumsq ----------------
__global__ void fin_iu_k(float* __restrict__ stats,
                         const unsigned short* __restrict__ Wf, // layer base [2][10240]
                         const float* __restrict__ gi, const float* __restrict__ bbi,
                         const float* __restrict__ gu, const float* __restrict__ bbu,
                         float* __restrict__ coeff) {
    int j = threadIdx.x; // 64 = out col
    int nf = j >> 4, rr = j & 15;
    float muI = 0.f, muU = 0.f;
    for (int k = 0; k < 160; ++k) {
        float zs = (k < 64) ? stats[256 + k] : (k < 128) ? stats[320 + k - 64] : stats[384 + k - 128];
        int kt = k >> 5, rem = k & 31, cc = rem >> 3, ii = rem & 7;
        int f = kt * 2048 + nf * 512 + (cc * 16 + rr) * 8 + ii;
        muI += zs * b2f(Wf[f]);
        muU += zs * b2f(Wf[10240 + f]);
    }
    const float invE = 1.f / (float)NE;
    muI *= invE; muU *= invE;
    float varI = stats[j] * invE - muI * muI;
    float sI = gi[j] * rsqrtf(varI + 1e-5f);
    coeff[j] = sI;
    coeff[64 + j] = bbi[j] - muI * sI;
    float varU = stats[64 + j] * invE - muU * muU;
    float sU = gu[j] * rsqrtf(varU + 1e-5f);
    coeff[128 + j] = sU;
    coeff[192 + j] = bbu[j] - muU * sU;
    stats[128 + j] = 0.f;  // msum
    stats[192 + j] = 0.f;  // msq
}

// ---------------- node-parallel apply: BN + sig*softplus + exact segment sum (no atomics) ----------------
__global__ __launch_bounds__(256) void apply_node_k(const unsigned short* __restrict__ preIb,
                                                    const unsigned short* __restrict__ preUb,
                                                    const int* __restrict__ eoff,
                                                    const float* __restrict__ coeff,
                                                    float* __restrict__ m) {
    int t = blockIdx.x * 256 + threadIdx.x; // NN*16 threads
    int chunk = t & 15;
    int n = t >> 4;
    if (n >= NN) return;
    float sIv[4], tIv[4], sUv[4], tUv[4];
#pragma unroll
    for (int q = 0; q < 4; ++q) {
        int col = chunk * 4 + q;
        sIv[q] = coeff[col];       tIv[q] = coeff[64 + col];
        sUv[q] = coeff[128 + col]; tUv[q] = coeff[192 + col];
    }
    int b = eoff[n], e = eoff[n + 1];
    float acc[4] = {0.f, 0.f, 0.f, 0.f};
    for (int p = b; p < e; ++p) {
        ushort4 vi = *(const ushort4*)(preIb + (size_t)p * DD + chunk * 4);
        ushort4 vu = *(const ushort4*)(preUb + (size_t)p * DD + chunk * 4);
        acc[0] += sig_(b2f(vi.x) * sIv[0] + tIv[0]) * sp_(b2f(vu.x) * sUv[0] + tUv[0]);
        acc[1] += sig_(b2f(vi.y) * sIv[1] + tIv[1]) * sp_(b2f(vu.y) * sUv[1] + tUv[1]);
        acc[2] += sig_(b2f(vi.z) * sIv[2] + tIv[2]) * sp_(b2f(vu.z) * sUv[2] + tUv[2]);
        acc[3] += sig_(b2f(vi.w) * sIv[3] + tIv[3]) * sp_(b2f(vu.w) * sUv[3] + tUv[3]);
    }
    float4 v; v.x = acc[0]; v.y = acc[1]; v.z = acc[2]; v.w = acc[3];
    *(float4*)(m + (size_t)n * DD + chunk * 4) = v;
}

// ---------------- m column stats ----------------
__global__ __launch_bounds__(256) void m_stats_k(const float* __restrict__ m,
                                                 float* __restrict__ msum,
                                                 float* __restrict__ msq) {
    __shared__ float rs[256], rq[256];
    int t = threadIdx.x;
    int col = t & 63;
    int row0 = blockIdx.x * 4 + (t >> 6);
    int rstride = gridDim.x * 4;
    float s = 0.f, q = 0.f;
    for (int n = row0; n < NN; n += rstride) {
        float v = m[(size_t)n * DD + col];
        s += v; q += v * v;
    }
    rs[t] = s; rq[t] = q;
    __syncthreads();
    if (t < 64) {
        s = rs[t] + rs[t + 64] + rs[t + 128] + rs[t + 192];
        q = rq[t] + rq[t + 64] + rq[t + 128] + rq[t + 192];
        unsafeAtomicAdd(&msum[t], s);
        unsafeAtomicAdd(&msq[t], q);
    }
}

// ---------------- finalize BN(m); zero next layer's accumulators ----------------
__global__ void fin_n_k(float* __restrict__ stats,
                        const float* __restrict__ gn, const float* __restrict__ bbn,
                        float* __restrict__ coeffN) {
    int j = threadIdx.x; // 64
    const float invN = 1.f / (float)NN;
    float mu = stats[128 + j] * invN;
    float var = stats[192 + j] * invN - mu * mu;
    float s = gn[j] * rsqrtf(var + 1e-5f);
    coeffN[j] = s;
    coeffN[64 + j] = bbn[j] - mu * s;
    stats[256 + j] = 0.f;  // zsumS
    stats[320 + j] = 0.f;  // zsumD
}

// ---------------- h = sp(h + bn(m)); final layer fuses graph pooling ----------------
__global__ void h_update_k(float* __restrict__ h, unsigned short* __restrict__ hb,
                           const float* __restrict__ m,
                           const float* __restrict__ coeffN,
                           const int* __restrict__ gid,
                           float* __restrict__ pool, float* __restrict__ pcnt,
                           int fin) {
    int i = blockIdx.x * 256 + threadIdx.x;
    if (i >= NN * DD) return;
    int j = i & 63;
    float v = h[i] + m[i] * coeffN[j] + coeffN[64 + j];
    v = sp_(v);
    if (fin) {
        int n = i >> 6;
        int g = gid[n];
        unsafeAtomicAdd(&pool[(size_t)g * DD + j], v);
        if (j == 0) unsafeAtomicAdd(&pcnt[g], 1.f);
    } else {
        h[i] = v;
        hb[i] = f2b(v);
    }
}

// ---------------- head ----------------
__global__ __launch_bounds__(128) void head_k(const float* __restrict__ pool,
                                              const float* __restrict__ pcnt,
                                              const float* __restrict__ fcW,
                                              const float* __restrict__ fcb,
                                              const float* __restrict__ oW,
                                              const float* __restrict__ ob,
                                              float* __restrict__ out) {
    int g = blockIdx.x;
    int t = threadIdx.x; // 128
    __shared__ float feats[DD];
    __shared__ float red[FF];
    if (t < DD) {
        float c = fmaxf(pcnt[g], 1.f);
        feats[t] = sp_(pool[(size_t)g * DD + t] / c);
    }
    __syncthreads();
    float a = fcb[t];
#pragma unroll 1
    for (int j = 0; j < DD; ++j) a += feats[j] * fcW[j * FF + t];
    float y = sp_(sp_(a));
    red[t] = y * oW[t];
    __syncthreads();
    for (int s2 = 64; s2 >= 1; s2 >>= 1) {
        if (t < s2) red[t] += red[t + s2];
        __syncthreads();
    }
    if (t == 0) out[g] = red[0] + ob[0];
}

extern "C" void kernel_launch(void* const* d_in, const int* in_sizes, int n_in,
                              void* d_out, int out_size, void* d_ws, size_t ws_size,
                              hipStream_t stream) {
    const float* af   = (const float*)d_in[0];
    const float* bond = (const float*)d_in[1];
    const int*   src  = (const int*)d_in[2];
    const int*   dst  = (const int*)d_in[3];
    const int*   gid  = (const int*)d_in[4];
    const float* embW = (const float*)d_in[5];
    const float* embB = (const float*)d_in[6];
    const float* Wi   = (const float*)d_in[7];
    const float* gi   = (const float*)d_in[9];
    const float* bbi  = (const float*)d_in[10];
    const float* Wu   = (const float*)d_in[11];
    const float* gu   = (const float*)d_in[13];
    const float* bbu  = (const float*)d_in[14];
    const float* gn   = (const float*)d_in[15];
    const float* bbn  = (const float*)d_in[16];
    const float* fcW  = (const float*)d_in[17];
    const float* fcb  = (const float*)d_in[18];
    const float* oW   = (const float*)d_in[19];
    const float* ob   = (const float*)d_in[20];
    float* out = (float*)d_out;

    char* ws = (char*)d_ws;
    size_t off = 0;
    auto take = [&](size_t bytes) {
        size_t o = off;
        off += (bytes + 255) & ~(size_t)255;
        return o;
    };
    float* h     = (float*)(ws + take((size_t)NN * DD * 4));
    float* m     = (float*)(ws + take((size_t)NN * DD * 4));
    float* stats = (float*)(ws + take(512 * 4));
    float* coeff = (float*)(ws + take(512 * 4)); // [sI,tI,sU,tU | sN,tN]
    float* pq    = (float*)(ws + take((size_t)2 * 64 * NBLK * 4)); // 1.28 MB partial sumsq
    float* pool  = (float*)(ws + take((size_t)NG * DD * 4)); // 32768 B
    float* pcnt  = (float*)(ws + take((size_t)NG * 4));      // 512 B padded
    int* ecount  = (int*)(ws + take((size_t)NN * 4));        // indeg
    int* ocount  = (int*)(ws + take((size_t)NN * 4));        // outdeg (contiguous after ecount)
    int* eoff    = (int*)(ws + take((size_t)(NN + 1) * 4));
    int* ecur    = (int*)(ws + take((size_t)NN * 4));
    int* ssrc    = (int*)(ws + take((size_t)NE * 4));
    int* sdst    = (int*)(ws + take((size_t)NE * 4));
    float* bond_s = (float*)(ws + take((size_t)NE * 4));
    unsigned short* hb    = (unsigned short*)(ws + take((size_t)NN * DD * 2));
    unsigned short* preIb = (unsigned short*)(ws + take((size_t)NE * DD * 2));
    unsigned short* preUb = (unsigned short*)(ws + take((size_t)NE * DD * 2));
    unsigned short* Wf    = (unsigned short*)(ws + take((size_t)6 * 10240 * 2));

    // zero: pool+pcnt (contiguous), ecount+ocount (contiguous), stats
    hipMemsetAsync((void*)pool, 0, 32768 + 512, stream);
    hipMemsetAsync((void*)ecount, 0, 2 * (((size_t)NN * 4 + 255) & ~(size_t)255), stream);
    hipMemsetAsync((void*)stats, 0, 512 * 4, stream);

    prep_wf_k<<<6, 256, 0, stream>>>(Wi, Wu, Wf);
    embed_k<<<(NN + 255) / 256, 256, 0, stream>>>(af, embW, embB, h, hb);

    cnt_edges_k<<<(NE + 255) / 256, 256, 0, stream>>>(src, dst, ecount, ocount);
    csr_scan_k<<<1, 1024, 0, stream>>>(ecount, eoff, ecur);
    fill_edges_k<<<(NE + 255) / 256, 256, 0, stream>>>(src, dst, bond, ecur, ssrc, sdst, bond_s);
    rbfsum_k<<<64, 256, 0, stream>>>(bond, stats + 384);

    for (int l = 0; l < 3; ++l) {
        const unsigned short* Wfl = Wf + (size_t)l * 2 * 10240;
        zsum_node_k<<<128, 256, 0, stream>>>(hb, ocount, ecount, stats + 256, stats + 320);
        edge_pre2_k<<<2 * NBLK, 256, 0, stream>>>(hb, bond_s, Wfl, ssrc, sdst, preIb, preUb, pq);
        qred_k<<<128, 256, 0, stream>>>(pq, stats);
        fin_iu_k<<<1, 64, 0, stream>>>(stats, Wfl, gi + l * DD, bbi + l * DD,
                                       gu + l * DD, bbu + l * DD, coeff);
        apply_node_k<<<NN * 16 / 256, 256, 0, stream>>>(preIb, preUb, eoff, coeff, m);
        m_stats_k<<<128, 256, 0, stream>>>(m, stats + 128, stats + 192);
        fin_n_k<<<1, 64, 0, stream>>>(stats, gn + l * DD, bbn + l * DD, coeff + 256);
        h_update_k<<<(NN * DD + 255) / 256, 256, 0, stream>>>(h, hb, m, coeff + 256,
                                                              gid, pool, pcnt, l == 2 ? 1 : 0);
    }

    head_k<<<NG, 128, 0, stream>>>(pool, pcnt, fcW, fcb, oW, ob, out);
}

// Round 7
// 732.899 us; speedup vs baseline: 1.9067x; 1.2162x over previous
//
#include <hip/hip_runtime.h>
#include <hip/hip_bf16.h>
#include <math.h>

#define NN 20000
#define NE 320000
#define NG 128
#define DD 64
#define FA 92
#define FF 128
#define NT (NE / 16)          // 16-edge MFMA tiles = 20000
#define NBLK 5000             // blocks per gate in edge_pre2 (1 tile per wave)
#define NAB 1250              // apply_node blocks
#define GAMMA 3.875f          // 31/8
#define CEN (8.0f / 31.0f)    // center spacing

typedef __attribute__((ext_vector_type(8))) short bf16x8;
typedef __attribute__((ext_vector_type(4))) float f32x4;

// stats layout (floats): [0]=qI, [64]=qU, [128]=msum, [192]=msq, [256]=zsumS, [320]=zsumD, [384]=zsumR(32)

__device__ __forceinline__ float sp_(float x) {
    return fmaxf(x, 0.f) + __logf(1.f + __expf(-fabsf(x)));
}
__device__ __forceinline__ float sig_(float x) {
    return 1.f / (1.f + __expf(-x));
}
__device__ __forceinline__ unsigned short f2b(float x) {
    __hip_bfloat16 b = __float2bfloat16(x);
    return *reinterpret_cast<unsigned short*>(&b);
}
__device__ __forceinline__ float b2f(unsigned short u) {
    return __uint_as_float((unsigned)u << 16);
}

// ---------------- embedding: h = af @ emb_W + emb_b (fp32 + bf16 copy) ----------------
__global__ __launch_bounds__(256) void embed_k(const float* __restrict__ af,
                                               const float* __restrict__ W,
                                               const float* __restrict__ b,
                                               float* __restrict__ h,
                                               unsigned short* __restrict__ hb) {
    __shared__ float Ws[FA * DD];
    for (int i = threadIdx.x * 4; i < FA * DD; i += 256 * 4)
        *(float4*)&Ws[i] = *(const float4*)&W[i];
    __syncthreads();
    int n = blockIdx.x * 256 + threadIdx.x;
    if (n >= NN) return;
    float acc[DD];
#pragma unroll
    for (int j = 0; j < DD; ++j) acc[j] = b[j];
    const float* row = af + (size_t)n * FA;
#pragma unroll 1
    for (int k4 = 0; k4 < FA / 4; ++k4) {
        float4 z = *(const float4*)(row + k4 * 4);
#pragma unroll
        for (int kk = 0; kk < 4; ++kk) {
            float a = ((const float*)&z)[kk];
            const float* wr = &Ws[(k4 * 4 + kk) * DD];
#pragma unroll
            for (int j = 0; j < DD; j += 4) {
                float4 w = *(const float4*)(wr + j);
                acc[j + 0] += a * w.x; acc[j + 1] += a * w.y;
                acc[j + 2] += a * w.z; acc[j + 3] += a * w.w;
            }
        }
    }
    float* o = h + (size_t)n * DD;
    unsigned short* ob = hb + (size_t)n * DD;
#pragma unroll
    for (int j = 0; j < DD; j += 4) {
        float4 v; v.x = acc[j]; v.y = acc[j + 1]; v.z = acc[j + 2]; v.w = acc[j + 3];
        *(float4*)(o + j) = v;
    }
#pragma unroll
    for (int j = 0; j < DD; ++j) ob[j] = f2b(acc[j]);
}

// ---------------- weight fragment prep: element = W[kt*32+8c+i][nf*16+r] ----------------
__global__ void prep_wf_k(const float* __restrict__ Wi, const float* __restrict__ Wu,
                          unsigned short* __restrict__ Wf) {
    int b = blockIdx.x;          // 0..5 : layer*2 + gate
    int l = b >> 1, g = b & 1;
    const float* W = (g ? Wu : Wi) + (size_t)l * 160 * DD;
    for (int f = threadIdx.x; f < 10240; f += 256) {
        int i = f & 7;
        int lane = (f >> 3) & 63;
        int nf = (f >> 9) & 3;
        int kt = f >> 11;
        int k = kt * 32 + 8 * (lane >> 4) + i;
        int col = nf * 16 + (lane & 15);
        Wf[(size_t)b * 10240 + f] = f2b(W[k * DD + col]);
    }
}

// ---------------- CSR build (sorted-by-dst edge order) ----------------
__global__ void cnt_edges_k(const int* __restrict__ src, const int* __restrict__ dst,
                            int* __restrict__ icnt, int* __restrict__ ocnt) {
    int e = blockIdx.x * 256 + threadIdx.x;
    if (e < NE) {
        atomicAdd(&icnt[dst[e]], 1);
        atomicAdd(&ocnt[src[e]], 1);
    }
}

__global__ __launch_bounds__(1024) void csr_scan_k(const int* __restrict__ cnt,
                                                   int* __restrict__ off,
                                                   int* __restrict__ cur) {
    __shared__ int part[1024];
    int t = threadIdx.x;
    int base = t * 20;
    int s = 0;
    for (int i = 0; i < 20; ++i) { int idx = base + i; if (idx < NN) s += cnt[idx]; }
    part[t] = s;
    __syncthreads();
    for (int ofs = 1; ofs < 1024; ofs <<= 1) {
        int v = (t >= ofs) ? part[t - ofs] : 0;
        __syncthreads();
        part[t] += v;
        __syncthreads();
    }
    int run = (t == 0) ? 0 : part[t - 1];
    for (int i = 0; i < 20; ++i) {
        int idx = base + i;
        if (idx < NN) { off[idx] = run; cur[idx] = run; run += cnt[idx]; }
    }
    if (t == 1023) off[NN] = run;
}

__global__ void fill_edges_k(const int* __restrict__ src, const int* __restrict__ dst,
                             const float* __restrict__ bond,
                             int* __restrict__ cur, int* __restrict__ ssrc,
                             int* __restrict__ sdst, float* __restrict__ bond_s) {
    int e = blockIdx.x * 256 + threadIdx.x;
    if (e < NE) {
        int d = dst[e];
        int p = atomicAdd(&cur[d], 1);
        ssrc[p] = src[e];
        sdst[p] = d;
        bond_s[p] = bond[e];
    }
}

// ---------------- one-time: column sum of bf16-rounded rbf over all edges ----------------
// 32 lanes share one broadcast bond load; col = lane&31.
__global__ __launch_bounds__(256) void rbfsum_k(const float* __restrict__ bond,
                                                float* __restrict__ zr) {
    __shared__ float part[4][32];
    int lane = threadIdx.x & 63;
    int w = threadIdx.x >> 6;
    int col = lane & 31;
    int half = lane >> 5;
    int slot = (blockIdx.x * 4 + w) * 2 + half;
    int nslots = gridDim.x * 8;
    float cen = (float)col * CEN;
    float a = 0.f;
    for (int e = slot; e < NE; e += nslots) {
        float u = bond[e] - cen;
        a += b2f(f2b(__expf(-GAMMA * u * u)));
    }
    a += __shfl_xor(a, 32, 64);
    if (half == 0) part[w][col] = a;
    __syncthreads();
    if (threadIdx.x < 32) {
        float s = part[0][threadIdx.x] + part[1][threadIdx.x] +
                  part[2][threadIdx.x] + part[3][threadIdx.x];
        unsafeAtomicAdd(&zr[threadIdx.x], s);
    }
}

// ---------------- per layer: degree-weighted column sums of hb ----------------
__global__ __launch_bounds__(256) void zsum_node_k(const unsigned short* __restrict__ hb,
                                                   const int* __restrict__ ocnt,
                                                   const int* __restrict__ icnt,
                                                   float* __restrict__ zS,
                                                   float* __restrict__ zD) {
    int t = blockIdx.x * 256 + threadIdx.x;
    int col = t & 63;
    int n0 = t >> 6;
    int nstride = (gridDim.x * 256) >> 6;
    float aS = 0.f, aD = 0.f;
    for (int n = n0; n < NN; n += nstride) {
        float v = b2f(hb[(size_t)n * DD + col]);
        aS += (float)ocnt[n] * v;
        aD += (float)icnt[n] * v;
    }
    unsafeAtomicAdd(&zS[col], aS);
    unsafeAtomicAdd(&zD[col], aD);
}

// ---------------- gather-GEMM, gate-split, 1 tile/wave: pre (bf16) + per-block sumsq ----------------
__global__ __launch_bounds__(256) void edge_pre2_k(const unsigned short* __restrict__ hb,
                                                   const float* __restrict__ bond_s,
                                                   const unsigned short* __restrict__ Wf, // layer base [2][10240]
                                                   const int* __restrict__ ssrc,
                                                   const int* __restrict__ sdst,
                                                   unsigned short* __restrict__ preIb,
                                                   unsigned short* __restrict__ preUb,
                                                   float* __restrict__ pq) {
    __shared__ bf16x8 WfS[1280];     // 20 KB : this gate's fragments
    __shared__ float qred_s[4][64];
    const int g = blockIdx.x & 1;
    const int bidx = blockIdx.x >> 1;       // 0..NBLK-1
    const int lane = threadIdx.x & 63;
    const int w = threadIdx.x >> 6;
    const int r = lane & 15;   // edge-within-tile
    const int c = lane >> 4;   // k-chunk / output col group
    const int tile = bidx * 4 + w;          // exactly NT tiles per gate
    const int e = tile * 16 + r;

    // issue index loads + gathers before staging so they overlap the LDS fill
    int es = ssrc[e];
    int ed = sdst[e];
    float bd = bond_s[e];
    bf16x8 a0 = *(const bf16x8*)(hb + (size_t)es * DD + c * 8);
    bf16x8 a1 = *(const bf16x8*)(hb + (size_t)es * DD + 32 + c * 8);
    bf16x8 a2 = *(const bf16x8*)(hb + (size_t)ed * DD + c * 8);
    bf16x8 a3 = *(const bf16x8*)(hb + (size_t)ed * DD + 32 + c * 8);
    bf16x8 a4;
#pragma unroll
    for (int i = 0; i < 8; ++i) {
        float cen = (float)(8 * c + i) * CEN;
        float u = bd - cen;
        a4[i] = (short)f2b(__expf(-GAMMA * u * u));
    }

    {
        const bf16x8* Wf8 = (const bf16x8*)Wf + (size_t)g * 1280;
        for (int i = threadIdx.x; i < 1280; i += 256) WfS[i] = Wf8[i];
    }
    __syncthreads();

    f32x4 acc[4];
#pragma unroll
    for (int nf = 0; nf < 4; ++nf) {
        f32x4 z4 = {0.f, 0.f, 0.f, 0.f};
        acc[nf] = z4;
    }
#pragma unroll
    for (int kt = 0; kt < 5; ++kt) {
        bf16x8 a = (kt == 0) ? a0 : (kt == 1) ? a1 : (kt == 2) ? a2 : (kt == 3) ? a3 : a4;
#pragma unroll
        for (int nf = 0; nf < 4; ++nf) {
            // swapped operands: A = W^T fragment, B = z fragment  =>  D[outcol][edge]
            acc[nf] = __builtin_amdgcn_mfma_f32_16x16x32_bf16(WfS[(kt * 4 + nf) * 64 + lane], a, acc[nf], 0, 0, 0);
        }
    }

    unsigned short* pre = (g ? preUb : preIb) + (size_t)e * DD + c * 4;
    float q[16];
#pragma unroll
    for (int nf = 0; nf < 4; ++nf) {
        ushort4 o;
        o.x = f2b(acc[nf][0]); o.y = f2b(acc[nf][1]);
        o.z = f2b(acc[nf][2]); o.w = f2b(acc[nf][3]);
        *(ushort4*)(pre + nf * 16) = o;
#pragma unroll
        for (int j = 0; j < 4; ++j)
            q[nf * 4 + j] = acc[nf][j] * acc[nf][j];
    }

    // reduce sumsq across the 16 r-lanes of each c-group
    float vq = 0.f;
#pragma unroll
    for (int s = 0; s < 16; ++s) {
        float a = q[s];
        a += __shfl_xor(a, 1, 64); a += __shfl_xor(a, 2, 64);
        a += __shfl_xor(a, 4, 64); a += __shfl_xor(a, 8, 64);
        if (r == s) vq = a;
    }
    int col = (r >> 2) * 16 + c * 4 + (r & 3);
    qred_s[w][col] = vq;
    __syncthreads();
    if (w == 0) {
        float s4 = qred_s[0][lane] + qred_s[1][lane] + qred_s[2][lane] + qred_s[3][lane];
        pq[((size_t)g * 64 + lane) * NBLK + bidx] = s4;  // per-block partial, no atomics
    }
}

// ---------------- generic row reduce: out[row] = sum(part[row][0..len)) ----------------
__global__ __launch_bounds__(256) void red_k(const float* __restrict__ part,
                                             float* __restrict__ out, int len) {
    __shared__ float red[256];
    const float* row = part + (size_t)blockIdx.x * len;
    float s = 0.f;
    for (int i = threadIdx.x; i < len; i += 256) s += row[i];
    red[threadIdx.x] = s;
    __syncthreads();
    for (int ofs = 128; ofs >= 1; ofs >>= 1) {
        if (threadIdx.x < ofs) red[threadIdx.x] += red[threadIdx.x + ofs];
        __syncthreads();
    }
    if (threadIdx.x == 0) out[blockIdx.x] = red[0];
}

// ---------------- BN coeffs for gate/update: mean via linearity, var via sumsq ----------------
__global__ void fin_iu_k(const float* __restrict__ stats,
                         const unsigned short* __restrict__ Wf, // layer base [2][10240]
                         const float* __restrict__ gi, const float* __restrict__ bbi,
                         const float* __restrict__ gu, const float* __restrict__ bbu,
                         float* __restrict__ coeff) {
    int j = threadIdx.x; // 64 = out col
    int nf = j >> 4, rr = j & 15;
    float muI = 0.f, muU = 0.f;
    for (int k = 0; k < 160; ++k) {
        float zs = (k < 64) ? stats[256 + k] : (k < 128) ? stats[320 + k - 64] : stats[384 + k - 128];
        int kt = k >> 5, rem = k & 31, cc = rem >> 3, ii = rem & 7;
        int f = kt * 2048 + nf * 512 + (cc * 16 + rr) * 8 + ii;
        muI += zs * b2f(Wf[f]);
        muU += zs * b2f(Wf[10240 + f]);
    }
    const float invE = 1.f / (float)NE;
    muI *= invE; muU *= invE;
    float varI = stats[j] * invE - muI * muI;
    float sI = gi[j] * rsqrtf(varI + 1e-5f);
    coeff[j] = sI;
    coeff[64 + j] = bbi[j] - muI * sI;
    float varU = stats[64 + j] * invE - muU * muU;
    float sU = gu[j] * rsqrtf(varU + 1e-5f);
    coeff[128 + j] = sU;
    coeff[192 + j] = bbu[j] - muU * sU;
}

// ---------------- node-parallel apply + fused m column stats (per-block partials) ----------------
__global__ __launch_bounds__(256) void apply_node_k(const unsigned short* __restrict__ preIb,
                                                    const unsigned short* __restrict__ preUb,
                                                    const int* __restrict__ eoff,
                                                    const float* __restrict__ coeff,
                                                    float* __restrict__ m,
                                                    float* __restrict__ mpart) {
    __shared__ float ps[256][4];
    __shared__ float pq2[256][4];
    int t = blockIdx.x * 256 + threadIdx.x; // NN*16 threads exactly
    int chunk = t & 15;
    int n = t >> 4;
    float sIv[4], tIv[4], sUv[4], tUv[4];
#pragma unroll
    for (int q = 0; q < 4; ++q) {
        int col = chunk * 4 + q;
        sIv[q] = coeff[col];       tIv[q] = coeff[64 + col];
        sUv[q] = coeff[128 + col]; tUv[q] = coeff[192 + col];
    }
    int b = eoff[n], e = eoff[n + 1];
    float acc[4] = {0.f, 0.f, 0.f, 0.f};
    for (int p = b; p < e; ++p) {
        ushort4 vi = *(const ushort4*)(preIb + (size_t)p * DD + chunk * 4);
        ushort4 vu = *(const ushort4*)(preUb + (size_t)p * DD + chunk * 4);
        acc[0] += sig_(b2f(vi.x) * sIv[0] + tIv[0]) * sp_(b2f(vu.x) * sUv[0] + tUv[0]);
        acc[1] += sig_(b2f(vi.y) * sIv[1] + tIv[1]) * sp_(b2f(vu.y) * sUv[1] + tUv[1]);
        acc[2] += sig_(b2f(vi.z) * sIv[2] + tIv[2]) * sp_(b2f(vu.z) * sUv[2] + tUv[2]);
        acc[3] += sig_(b2f(vi.w) * sIv[3] + tIv[3]) * sp_(b2f(vu.w) * sUv[3] + tUv[3]);
    }
    float4 v; v.x = acc[0]; v.y = acc[1]; v.z = acc[2]; v.w = acc[3];
    *(float4*)(m + (size_t)n * DD + chunk * 4) = v;
#pragma unroll
    for (int q = 0; q < 4; ++q) {
        ps[threadIdx.x][q] = acc[q];
        pq2[threadIdx.x][q] = acc[q] * acc[q];
    }
    __syncthreads();
    if (threadIdx.x < 64) {
        int cc = threadIdx.x;
        int ch = cc >> 2, qq = cc & 3;
        float s = 0.f, q2 = 0.f;
#pragma unroll
        for (int nn = 0; nn < 16; ++nn) {
            s += ps[nn * 16 + ch][qq];
            q2 += pq2[nn * 16 + ch][qq];
        }
        mpart[(size_t)cc * NAB + blockIdx.x] = s;
        mpart[(size_t)(64 + cc) * NAB + blockIdx.x] = q2;
    }
}

// ---------------- finalize BN(m); zero next layer's zsum accumulators ----------------
__global__ void fin_n_k(float* __restrict__ stats,
                        const float* __restrict__ gn, const float* __restrict__ bbn,
                        float* __restrict__ coeffN) {
    int j = threadIdx.x; // 64
    const float invN = 1.f / (float)NN;
    float mu = stats[128 + j] * invN;
    float var = stats[192 + j] * invN - mu * mu;
    float s = gn[j] * rsqrtf(var + 1e-5f);
    coeffN[j] = s;
    coeffN[64 + j] = bbn[j] - mu * s;
    stats[256 + j] = 0.f;  // zsumS
    stats[320 + j] = 0.f;  // zsumD
}

// ---------------- h = sp(h + bn(m)); final layer fuses graph pooling ----------------
__global__ void h_update_k(float* __restrict__ h, unsigned short* __restrict__ hb,
                           const float* __restrict__ m,
                           const float* __restrict__ coeffN,
                           const int* __restrict__ gid,
                           float* __restrict__ pool, float* __restrict__ pcnt,
                           int fin) {
    int i = blockIdx.x * 256 + threadIdx.x;
    if (i >= NN * DD) return;
    int j = i & 63;
    float v = h[i] + m[i] * coeffN[j] + coeffN[64 + j];
    v = sp_(v);
    if (fin) {
        int n = i >> 6;
        int g = gid[n];
        unsafeAtomicAdd(&pool[(size_t)g * DD + j], v);
        if (j == 0) unsafeAtomicAdd(&pcnt[g], 1.f);
    } else {
        h[i] = v;
        hb[i] = f2b(v);
    }
}

// ---------------- head ----------------
__global__ __launch_bounds__(128) void head_k(const float* __restrict__ pool,
                                              const float* __restrict__ pcnt,
                                              const float* __restrict__ fcW,
                                              const float* __restrict__ fcb,
                                              const float* __restrict__ oW,
                                              const float* __restrict__ ob,
                                              float* __restrict__ out) {
    int g = blockIdx.x;
    int t = threadIdx.x; // 128
    __shared__ float feats[DD];
    __shared__ float red[FF];
    if (t < DD) {
        float c = fmaxf(pcnt[g], 1.f);
        feats[t] = sp_(pool[(size_t)g * DD + t] / c);
    }
    __syncthreads();
    float a = fcb[t];
#pragma unroll 1
    for (int j = 0; j < DD; ++j) a += feats[j] * fcW[j * FF + t];
    float y = sp_(sp_(a));
    red[t] = y * oW[t];
    __syncthreads();
    for (int s2 = 64; s2 >= 1; s2 >>= 1) {
        if (t < s2) red[t] += red[t + s2];
        __syncthreads();
    }
    if (t == 0) out[g] = red[0] + ob[0];
}

extern "C" void kernel_launch(void* const* d_in, const int* in_sizes, int n_in,
                              void* d_out, int out_size, void* d_ws, size_t ws_size,
                              hipStream_t stream) {
    const float* af   = (const float*)d_in[0];
    const float* bond = (const float*)d_in[1];
    const int*   src  = (const int*)d_in[2];
    const int*   dst  = (const int*)d_in[3];
    const int*   gid  = (const int*)d_in[4];
    const float* embW = (const float*)d_in[5];
    const float* embB = (const float*)d_in[6];
    const float* Wi   = (const float*)d_in[7];
    const float* gi   = (const float*)d_in[9];
    const float* bbi  = (const float*)d_in[10];
    const float* Wu   = (const float*)d_in[11];
    const float* gu   = (const float*)d_in[13];
    const float* bbu  = (const float*)d_in[14];
    const float* gn   = (const float*)d_in[15];
    const float* bbn  = (const float*)d_in[16];
    const float* fcW  = (const float*)d_in[17];
    const float* fcb  = (const float*)d_in[18];
    const float* oW   = (const float*)d_in[19];
    const float* ob   = (const float*)d_in[20];
    float* out = (float*)d_out;

    char* ws = (char*)d_ws;
    size_t off = 0;
    auto take = [&](size_t bytes) {
        size_t o = off;
        off += (bytes + 255) & ~(size_t)255;
        return o;
    };
    float* h     = (float*)(ws + take((size_t)NN * DD * 4));
    float* m     = (float*)(ws + take((size_t)NN * DD * 4));
    float* stats = (float*)(ws + take(512 * 4));
    float* coeff = (float*)(ws + take(512 * 4)); // [sI,tI,sU,tU | sN,tN]
    float* pq    = (float*)(ws + take((size_t)2 * 64 * NBLK * 4)); // 2.56 MB partial sumsq
    float* mpart = (float*)(ws + take((size_t)128 * NAB * 4));     // 640 KB m-stat partials
    float* pool  = (float*)(ws + take((size_t)NG * DD * 4)); // 32768 B
    float* pcnt  = (float*)(ws + take((size_t)NG * 4));      // 512 B padded
    int* ecount  = (int*)(ws + take((size_t)NN * 4));        // indeg
    int* ocount  = (int*)(ws + take((size_t)NN * 4));        // outdeg (contiguous after ecount)
    int* eoff    = (int*)(ws + take((size_t)(NN + 1) * 4));
    int* ecur    = (int*)(ws + take((size_t)NN * 4));
    int* ssrc    = (int*)(ws + take((size_t)NE * 4));
    int* sdst    = (int*)(ws + take((size_t)NE * 4));
    float* bond_s = (float*)(ws + take((size_t)NE * 4));
    unsigned short* hb    = (unsigned short*)(ws + take((size_t)NN * DD * 2));
    unsigned short* preIb = (unsigned short*)(ws + take((size_t)NE * DD * 2));
    unsigned short* preUb = (unsigned short*)(ws + take((size_t)NE * DD * 2));
    unsigned short* Wf    = (unsigned short*)(ws + take((size_t)6 * 10240 * 2));

    // zero: pool+pcnt (contiguous), ecount+ocount (contiguous), stats
    hipMemsetAsync((void*)pool, 0, 32768 + 512, stream);
    hipMemsetAsync((void*)ecount, 0, 2 * (((size_t)NN * 4 + 255) & ~(size_t)255), stream);
    hipMemsetAsync((void*)stats, 0, 512 * 4, stream);

    prep_wf_k<<<6, 256, 0, stream>>>(Wi, Wu, Wf);
    embed_k<<<(NN + 255) / 256, 256, 0, stream>>>(af, embW, embB, h, hb);

    cnt_edges_k<<<(NE + 255) / 256, 256, 0, stream>>>(src, dst, ecount, ocount);
    csr_scan_k<<<1, 1024, 0, stream>>>(ecount, eoff, ecur);
    fill_edges_k<<<(NE + 255) / 256, 256, 0, stream>>>(src, dst, bond, ecur, ssrc, sdst, bond_s);
    rbfsum_k<<<512, 256, 0, stream>>>(bond, stats + 384);

    for (int l = 0; l < 3; ++l) {
        const unsigned short* Wfl = Wf + (size_t)l * 2 * 10240;
        zsum_node_k<<<128, 256, 0, stream>>>(hb, ocount, ecount, stats + 256, stats + 320);
        edge_pre2_k<<<2 * NBLK, 256, 0, stream>>>(hb, bond_s, Wfl, ssrc, sdst, preIb, preUb, pq);
        red_k<<<128, 256, 0, stream>>>(pq, stats, NBLK);
        fin_iu_k<<<1, 64, 0, stream>>>(stats, Wfl, gi + l * DD, bbi + l * DD,
                                       gu + l * DD, bbu + l * DD, coeff);
        apply_node_k<<<NAB, 256, 0, stream>>>(preIb, preUb, eoff, coeff, m, mpart);
        red_k<<<128, 256, 0, stream>>>(mpart, stats + 128, NAB);
        fin_n_k<<<1, 64, 0, stream>>>(stats, gn + l * DD, bbn + l * DD, coeff + 256);
        h_update_k<<<(NN * DD + 255) / 256, 256, 0, stream>>>(h, hb, m, coeff + 256,
                                                              gid, pool, pcnt, l == 2 ? 1 : 0);
    }

    head_k<<<NG, 128, 0, stream>>>(pool, pcnt, fcW, fcb, oW, ob, out);
}

// Round 8
// 710.282 us; speedup vs baseline: 1.9675x; 1.0318x over previous
//
#include <hip/hip_runtime.h>
#include <hip/hip_bf16.h>
#include <math.h>

#define NN 20000
#define NE 320000
#define NG 128
#define DD 64
#define FA 92
#define FF 128
#define NT (NE / 16)          // 16-edge MFMA tiles = 20000
#define NBLK 5000             // blocks per gate in edge_pre2 (1 tile per wave)
#define NAB 1250              // apply_node blocks
#define NHB 625               // h_update blocks (NN*DD/8/256)
#define GAMMA 3.875f          // 31/8
#define CEN (8.0f / 31.0f)    // center spacing

typedef __attribute__((ext_vector_type(8))) short bf16x8;
typedef __attribute__((ext_vector_type(4))) float f32x4;

// stats layout (floats): [0]=qI, [64]=qU, [128]=msum, [192]=msq, [256]=zsumS, [320]=zsumD, [384]=zsumR(32)

__device__ __forceinline__ float sp_(float x) {
    return fmaxf(x, 0.f) + __logf(1.f + __expf(-fabsf(x)));
}
__device__ __forceinline__ float sig_(float x) {
    return 1.f / (1.f + __expf(-x));
}
__device__ __forceinline__ unsigned short f2b(float x) {
    __hip_bfloat16 b = __float2bfloat16(x);
    return *reinterpret_cast<unsigned short*>(&b);
}
__device__ __forceinline__ float b2f(unsigned short u) {
    return __uint_as_float((unsigned)u << 16);
}

// ---------------- embedding: h = af @ emb_W + emb_b (fp32 + bf16 copy) ----------------
__global__ __launch_bounds__(256) void embed_k(const float* __restrict__ af,
                                               const float* __restrict__ W,
                                               const float* __restrict__ b,
                                               float* __restrict__ h,
                                               unsigned short* __restrict__ hb) {
    __shared__ float Ws[FA * DD];
    for (int i = threadIdx.x * 4; i < FA * DD; i += 256 * 4)
        *(float4*)&Ws[i] = *(const float4*)&W[i];
    __syncthreads();
    int n = blockIdx.x * 256 + threadIdx.x;
    if (n >= NN) return;
    float acc[DD];
#pragma unroll
    for (int j = 0; j < DD; ++j) acc[j] = b[j];
    const float* row = af + (size_t)n * FA;
#pragma unroll 1
    for (int k4 = 0; k4 < FA / 4; ++k4) {
        float4 z = *(const float4*)(row + k4 * 4);
#pragma unroll
        for (int kk = 0; kk < 4; ++kk) {
            float a = ((const float*)&z)[kk];
            const float* wr = &Ws[(k4 * 4 + kk) * DD];
#pragma unroll
            for (int j = 0; j < DD; j += 4) {
                float4 w = *(const float4*)(wr + j);
                acc[j + 0] += a * w.x; acc[j + 1] += a * w.y;
                acc[j + 2] += a * w.z; acc[j + 3] += a * w.w;
            }
        }
    }
    float* o = h + (size_t)n * DD;
    unsigned short* ob = hb + (size_t)n * DD;
#pragma unroll
    for (int j = 0; j < DD; j += 4) {
        float4 v; v.x = acc[j]; v.y = acc[j + 1]; v.z = acc[j + 2]; v.w = acc[j + 3];
        *(float4*)(o + j) = v;
    }
#pragma unroll
    for (int j = 0; j < DD; ++j) ob[j] = f2b(acc[j]);
}

// ---------------- weight fragment prep: element = W[kt*32+8c+i][nf*16+r] ----------------
__global__ void prep_wf_k(const float* __restrict__ Wi, const float* __restrict__ Wu,
                          unsigned short* __restrict__ Wf) {
    int b = blockIdx.x;          // 0..5 : layer*2 + gate
    int l = b >> 1, g = b & 1;
    const float* W = (g ? Wu : Wi) + (size_t)l * 160 * DD;
    for (int f = threadIdx.x; f < 10240; f += 256) {
        int i = f & 7;
        int lane = (f >> 3) & 63;
        int nf = (f >> 9) & 3;
        int kt = f >> 11;
        int k = kt * 32 + 8 * (lane >> 4) + i;
        int col = nf * 16 + (lane & 15);
        Wf[(size_t)b * 10240 + f] = f2b(W[k * DD + col]);
    }
}

// ---------------- CSR build (sorted-by-dst edge order) ----------------
__global__ void cnt_edges_k(const int* __restrict__ src, const int* __restrict__ dst,
                            int* __restrict__ icnt, int* __restrict__ ocnt) {
    int e = blockIdx.x * 256 + threadIdx.x;
    if (e < NE) {
        atomicAdd(&icnt[dst[e]], 1);
        atomicAdd(&ocnt[src[e]], 1);
    }
}

__global__ __launch_bounds__(1024) void csr_scan_k(const int* __restrict__ cnt,
                                                   int* __restrict__ off,
                                                   int* __restrict__ cur) {
    __shared__ int part[1024];
    int t = threadIdx.x;
    int base = t * 20;
    int s = 0;
    for (int i = 0; i < 20; ++i) { int idx = base + i; if (idx < NN) s += cnt[idx]; }
    part[t] = s;
    __syncthreads();
    for (int ofs = 1; ofs < 1024; ofs <<= 1) {
        int v = (t >= ofs) ? part[t - ofs] : 0;
        __syncthreads();
        part[t] += v;
        __syncthreads();
    }
    int run = (t == 0) ? 0 : part[t - 1];
    for (int i = 0; i < 20; ++i) {
        int idx = base + i;
        if (idx < NN) { off[idx] = run; cur[idx] = run; run += cnt[idx]; }
    }
    if (t == 1023) off[NN] = run;
}

__global__ void fill_edges_k(const int* __restrict__ src, const int* __restrict__ dst,
                             const float* __restrict__ bond,
                             int* __restrict__ cur, int* __restrict__ ssrc,
                             int* __restrict__ sdst, float* __restrict__ bond_s) {
    int e = blockIdx.x * 256 + threadIdx.x;
    if (e < NE) {
        int d = dst[e];
        int p = atomicAdd(&cur[d], 1);
        ssrc[p] = src[e];
        sdst[p] = d;
        bond_s[p] = bond[e];
    }
}

// ---------------- one-time: column sum of bf16-rounded rbf over all edges ----------------
__global__ __launch_bounds__(256) void rbfsum_k(const float* __restrict__ bond,
                                                float* __restrict__ zr) {
    __shared__ float part[4][32];
    int lane = threadIdx.x & 63;
    int w = threadIdx.x >> 6;
    int col = lane & 31;
    int half = lane >> 5;
    int slot = (blockIdx.x * 4 + w) * 2 + half;
    int nslots = gridDim.x * 8;
    float cen = (float)col * CEN;
    float a = 0.f;
    for (int e = slot; e < NE; e += nslots) {
        float u = bond[e] - cen;
        a += b2f(f2b(__expf(-GAMMA * u * u)));
    }
    a += __shfl_xor(a, 32, 64);
    if (half == 0) part[w][col] = a;
    __syncthreads();
    if (threadIdx.x < 32) {
        float s = part[0][threadIdx.x] + part[1][threadIdx.x] +
                  part[2][threadIdx.x] + part[3][threadIdx.x];
        unsafeAtomicAdd(&zr[threadIdx.x], s);
    }
}

// ---------------- layer 0 only: degree-weighted column sums of hb ----------------
__global__ __launch_bounds__(256) void zsum_node_k(const unsigned short* __restrict__ hb,
                                                   const int* __restrict__ ocnt,
                                                   const int* __restrict__ icnt,
                                                   float* __restrict__ zS,
                                                   float* __restrict__ zD) {
    int t = blockIdx.x * 256 + threadIdx.x;
    int col = t & 63;
    int n0 = t >> 6;
    int nstride = (gridDim.x * 256) >> 6;
    float aS = 0.f, aD = 0.f;
    for (int n = n0; n < NN; n += nstride) {
        float v = b2f(hb[(size_t)n * DD + col]);
        aS += (float)ocnt[n] * v;
        aD += (float)icnt[n] * v;
    }
    unsafeAtomicAdd(&zS[col], aS);
    unsafeAtomicAdd(&zD[col], aD);
}

// ---------------- gather-GEMM, gate-split, 1 tile/wave: pre (bf16) + per-block sumsq ----------------
__global__ __launch_bounds__(256) void edge_pre2_k(const unsigned short* __restrict__ hb,
                                                   const float* __restrict__ bond_s,
                                                   const unsigned short* __restrict__ Wf, // layer base [2][10240]
                                                   const int* __restrict__ ssrc,
                                                   const int* __restrict__ sdst,
                                                   unsigned short* __restrict__ preIb,
                                                   unsigned short* __restrict__ preUb,
                                                   float* __restrict__ pq) {
    __shared__ bf16x8 WfS[1280];     // 20 KB : this gate's fragments
    __shared__ float qred_s[4][64];
    const int g = blockIdx.x & 1;
    const int bidx = blockIdx.x >> 1;       // 0..NBLK-1
    const int lane = threadIdx.x & 63;
    const int w = threadIdx.x >> 6;
    const int r = lane & 15;   // edge-within-tile
    const int c = lane >> 4;   // k-chunk / output col group
    const int tile = bidx * 4 + w;          // exactly NT tiles per gate
    const int e = tile * 16 + r;

    // issue index loads + gathers before staging so they overlap the LDS fill
    int es = ssrc[e];
    int ed = sdst[e];
    float bd = bond_s[e];
    bf16x8 a0 = *(const bf16x8*)(hb + (size_t)es * DD + c * 8);
    bf16x8 a1 = *(const bf16x8*)(hb + (size_t)es * DD + 32 + c * 8);
    bf16x8 a2 = *(const bf16x8*)(hb + (size_t)ed * DD + c * 8);
    bf16x8 a3 = *(const bf16x8*)(hb + (size_t)ed * DD + 32 + c * 8);
    bf16x8 a4;
#pragma unroll
    for (int i = 0; i < 8; ++i) {
        float cen = (float)(8 * c + i) * CEN;
        float u = bd - cen;
        a4[i] = (short)f2b(__expf(-GAMMA * u * u));
    }

    {
        const bf16x8* Wf8 = (const bf16x8*)Wf + (size_t)g * 1280;
        for (int i = threadIdx.x; i < 1280; i += 256) WfS[i] = Wf8[i];
    }
    __syncthreads();

    f32x4 acc[4];
#pragma unroll
    for (int nf = 0; nf < 4; ++nf) {
        f32x4 z4 = {0.f, 0.f, 0.f, 0.f};
        acc[nf] = z4;
    }
#pragma unroll
    for (int kt = 0; kt < 5; ++kt) {
        bf16x8 a = (kt == 0) ? a0 : (kt == 1) ? a1 : (kt == 2) ? a2 : (kt == 3) ? a3 : a4;
#pragma unroll
        for (int nf = 0; nf < 4; ++nf) {
            // swapped operands: A = W^T fragment, B = z fragment  =>  D[outcol][edge]
            acc[nf] = __builtin_amdgcn_mfma_f32_16x16x32_bf16(WfS[(kt * 4 + nf) * 64 + lane], a, acc[nf], 0, 0, 0);
        }
    }

    unsigned short* pre = (g ? preUb : preIb) + (size_t)e * DD + c * 4;
    float q[16];
#pragma unroll
    for (int nf = 0; nf < 4; ++nf) {
        ushort4 o;
        o.x = f2b(acc[nf][0]); o.y = f2b(acc[nf][1]);
        o.z = f2b(acc[nf][2]); o.w = f2b(acc[nf][3]);
        *(ushort4*)(pre + nf * 16) = o;
#pragma unroll
        for (int j = 0; j < 4; ++j)
            q[nf * 4 + j] = acc[nf][j] * acc[nf][j];
    }

    // reduce sumsq across the 16 r-lanes of each c-group
    float vq = 0.f;
#pragma unroll
    for (int s = 0; s < 16; ++s) {
        float a = q[s];
        a += __shfl_xor(a, 1, 64); a += __shfl_xor(a, 2, 64);
        a += __shfl_xor(a, 4, 64); a += __shfl_xor(a, 8, 64);
        if (r == s) vq = a;
    }
    int col = (r >> 2) * 16 + c * 4 + (r & 3);
    qred_s[w][col] = vq;
    __syncthreads();
    if (w == 0) {
        float s4 = qred_s[0][lane] + qred_s[1][lane] + qred_s[2][lane] + qred_s[3][lane];
        pq[((size_t)g * 64 + lane) * NBLK + bidx] = s4;  // per-block partial, no atomics
    }
}

// ---------------- generic row reduce: out[row] = sum(part[row][0..len)) ----------------
__global__ __launch_bounds__(256) void red_k(const float* __restrict__ part,
                                             float* __restrict__ out, int len) {
    __shared__ float red[256];
    const float* row = part + (size_t)blockIdx.x * len;
    float s = 0.f;
    for (int i = threadIdx.x; i < len; i += 256) s += row[i];
    red[threadIdx.x] = s;
    __syncthreads();
    for (int ofs = 128; ofs >= 1; ofs >>= 1) {
        if (threadIdx.x < ofs) red[threadIdx.x] += red[threadIdx.x + ofs];
        __syncthreads();
    }
    if (threadIdx.x == 0) out[blockIdx.x] = red[0];
}

// ---------------- BN coeffs for gate/update: mean via linearity, var via sumsq ----------------
__global__ void fin_iu_k(const float* __restrict__ stats,
                         const unsigned short* __restrict__ Wf, // layer base [2][10240]
                         const float* __restrict__ gi, const float* __restrict__ bbi,
                         const float* __restrict__ gu, const float* __restrict__ bbu,
                         float* __restrict__ coeff) {
    int j = threadIdx.x; // 64 = out col
    int nf = j >> 4, rr = j & 15;
    float muI = 0.f, muU = 0.f;
    for (int k = 0; k < 160; ++k) {
        float zs = (k < 64) ? stats[256 + k] : (k < 128) ? stats[320 + k - 64] : stats[384 + k - 128];
        int kt = k >> 5, rem = k & 31, cc = rem >> 3, ii = rem & 7;
        int f = kt * 2048 + nf * 512 + (cc * 16 + rr) * 8 + ii;
        muI += zs * b2f(Wf[f]);
        muU += zs * b2f(Wf[10240 + f]);
    }
    const float invE = 1.f / (float)NE;
    muI *= invE; muU *= invE;
    float varI = stats[j] * invE - muI * muI;
    float sI = gi[j] * rsqrtf(varI + 1e-5f);
    coeff[j] = sI;
    coeff[64 + j] = bbi[j] - muI * sI;
    float varU = stats[64 + j] * invE - muU * muU;
    float sU = gu[j] * rsqrtf(varU + 1e-5f);
    coeff[128 + j] = sU;
    coeff[192 + j] = bbu[j] - muU * sU;
}

// ---------------- node-parallel apply + fused m column stats (per-block partials) ----------------
__global__ __launch_bounds__(256) void apply_node_k(const unsigned short* __restrict__ preIb,
                                                    const unsigned short* __restrict__ preUb,
                                                    const int* __restrict__ eoff,
                                                    const float* __restrict__ coeff,
                                                    float* __restrict__ m,
                                                    float* __restrict__ mpart) {
    __shared__ float ps[256][4];
    __shared__ float pq2[256][4];
    int t = blockIdx.x * 256 + threadIdx.x; // NN*16 threads exactly
    int chunk = t & 15;
    int n = t >> 4;
    float sIv[4], tIv[4], sUv[4], tUv[4];
#pragma unroll
    for (int q = 0; q < 4; ++q) {
        int col = chunk * 4 + q;
        sIv[q] = coeff[col];       tIv[q] = coeff[64 + col];
        sUv[q] = coeff[128 + col]; tUv[q] = coeff[192 + col];
    }
    int b = eoff[n], e = eoff[n + 1];
    float acc[4] = {0.f, 0.f, 0.f, 0.f};
    for (int p = b; p < e; ++p) {
        ushort4 vi = *(const ushort4*)(preIb + (size_t)p * DD + chunk * 4);
        ushort4 vu = *(const ushort4*)(preUb + (size_t)p * DD + chunk * 4);
        acc[0] += sig_(b2f(vi.x) * sIv[0] + tIv[0]) * sp_(b2f(vu.x) * sUv[0] + tUv[0]);
        acc[1] += sig_(b2f(vi.y) * sIv[1] + tIv[1]) * sp_(b2f(vu.y) * sUv[1] + tUv[1]);
        acc[2] += sig_(b2f(vi.z) * sIv[2] + tIv[2]) * sp_(b2f(vu.z) * sUv[2] + tUv[2]);
        acc[3] += sig_(b2f(vi.w) * sIv[3] + tIv[3]) * sp_(b2f(vu.w) * sUv[3] + tUv[3]);
    }
    float4 v; v.x = acc[0]; v.y = acc[1]; v.z = acc[2]; v.w = acc[3];
    *(float4*)(m + (size_t)n * DD + chunk * 4) = v;
#pragma unroll
    for (int q = 0; q < 4; ++q) {
        ps[threadIdx.x][q] = acc[q];
        pq2[threadIdx.x][q] = acc[q] * acc[q];
    }
    __syncthreads();
    if (threadIdx.x < 64) {
        int cc = threadIdx.x;
        int ch = cc >> 2, qq = cc & 3;
        float s = 0.f, q2 = 0.f;
#pragma unroll
        for (int nn = 0; nn < 16; ++nn) {
            s += ps[nn * 16 + ch][qq];
            q2 += pq2[nn * 16 + ch][qq];
        }
        mpart[(size_t)cc * NAB + blockIdx.x] = s;
        mpart[(size_t)(64 + cc) * NAB + blockIdx.x] = q2;
    }
}

// ---------------- finalize BN(m) ----------------
__global__ void fin_n_k(const float* __restrict__ stats,
                        const float* __restrict__ gn, const float* __restrict__ bbn,
                        float* __restrict__ coeffN) {
    int j = threadIdx.x; // 64
    const float invN = 1.f / (float)NN;
    float mu = stats[128 + j] * invN;
    float var = stats[192 + j] * invN - mu * mu;
    float s = gn[j] * rsqrtf(var + 1e-5f);
    coeffN[j] = s;
    coeffN[64 + j] = bbn[j] - mu * s;
}

// ---------------- h = sp(h + bn(m)), 8-wide; fuses next-layer zsum partials / final pooling ----------------
__global__ __launch_bounds__(256) void h_update_k(float* __restrict__ h,
                                                  unsigned short* __restrict__ hb,
                                                  const float* __restrict__ m,
                                                  const float* __restrict__ coeffN,
                                                  const int* __restrict__ ocnt,
                                                  const int* __restrict__ icnt,
                                                  const int* __restrict__ gid,
                                                  float* __restrict__ pool,
                                                  float* __restrict__ pcnt,
                                                  float* __restrict__ zpart,
                                                  int fin) {
    __shared__ float wzs[4][8][8], wzd[4][8][8];
    int t = blockIdx.x * 256 + threadIdx.x;  // NN*DD/8 = 160000 threads exactly
    int n = t >> 3, ch = t & 7;
    int base = n * DD + ch * 8;
    float4 m0 = *(const float4*)(m + base);
    float4 m1 = *(const float4*)(m + base + 4);
    float4 h0 = *(const float4*)(h + base);
    float4 h1 = *(const float4*)(h + base + 4);
    float mv[8] = {m0.x, m0.y, m0.z, m0.w, m1.x, m1.y, m1.z, m1.w};
    float hv[8] = {h0.x, h0.y, h0.z, h0.w, h1.x, h1.y, h1.z, h1.w};
    unsigned short hbv[8];
#pragma unroll
    for (int q = 0; q < 8; ++q) {
        int col = ch * 8 + q;
        float v = sp_(hv[q] + mv[q] * coeffN[col] + coeffN[64 + col]);
        hv[q] = v;
        hbv[q] = f2b(v);
    }
    if (fin) {
        int g = gid[n];
#pragma unroll
        for (int q = 0; q < 8; ++q)
            unsafeAtomicAdd(&pool[(size_t)g * DD + ch * 8 + q], hv[q]);
        if (ch == 0) unsafeAtomicAdd(&pcnt[g], 1.f);
        return;
    }
    float4 o0, o1;
    o0.x = hv[0]; o0.y = hv[1]; o0.z = hv[2]; o0.w = hv[3];
    o1.x = hv[4]; o1.y = hv[5]; o1.z = hv[6]; o1.w = hv[7];
    *(float4*)(h + base) = o0;
    *(float4*)(h + base + 4) = o1;
    bf16x8 hb8;
#pragma unroll
    for (int q = 0; q < 8; ++q) hb8[q] = (short)hbv[q];
    *(bf16x8*)(hb + base) = hb8;

    // fused zsum partials for next layer: rows use the bf16-ROUNDED values
    float oc = (float)ocnt[n], ic = (float)icnt[n];
    float zs8[8], zd8[8];
#pragma unroll
    for (int q = 0; q < 8; ++q) {
        float r = b2f(hbv[q]);
        zs8[q] = r * oc;
        zd8[q] = r * ic;
    }
    // reduce over the 8 node-rows within each wave (lane = nrow*8 + ch)
#pragma unroll
    for (int mk = 8; mk <= 32; mk <<= 1) {
#pragma unroll
        for (int q = 0; q < 8; ++q) {
            zs8[q] += __shfl_xor(zs8[q], mk, 64);
            zd8[q] += __shfl_xor(zd8[q], mk, 64);
        }
    }
    int lane = threadIdx.x & 63;
    int w = threadIdx.x >> 6;
    if (lane < 8) {
#pragma unroll
        for (int q = 0; q < 8; ++q) {
            wzs[w][lane][q] = zs8[q];
            wzd[w][lane][q] = zd8[q];
        }
    }
    __syncthreads();
    if (threadIdx.x < 64) {
        int chh = threadIdx.x >> 3, qq = threadIdx.x & 7; // col = chh*8+qq = threadIdx.x
        float s = wzs[0][chh][qq] + wzs[1][chh][qq] + wzs[2][chh][qq] + wzs[3][chh][qq];
        float d = wzd[0][chh][qq] + wzd[1][chh][qq] + wzd[2][chh][qq] + wzd[3][chh][qq];
        zpart[(size_t)threadIdx.x * NHB + blockIdx.x] = s;
        zpart[(size_t)(64 + threadIdx.x) * NHB + blockIdx.x] = d;
    }
}

// ---------------- head ----------------
__global__ __launch_bounds__(128) void head_k(const float* __restrict__ pool,
                                              const float* __restrict__ pcnt,
                                              const float* __restrict__ fcW,
                                              const float* __restrict__ fcb,
                                              const float* __restrict__ oW,
                                              const float* __restrict__ ob,
                                              float* __restrict__ out) {
    int g = blockIdx.x;
    int t = threadIdx.x; // 128
    __shared__ float feats[DD];
    __shared__ float red[FF];
    if (t < DD) {
        float c = fmaxf(pcnt[g], 1.f);
        feats[t] = sp_(pool[(size_t)g * DD + t] / c);
    }
    __syncthreads();
    float a = fcb[t];
#pragma unroll 1
    for (int j = 0; j < DD; ++j) a += feats[j] * fcW[j * FF + t];
    float y = sp_(sp_(a));
    red[t] = y * oW[t];
    __syncthreads();
    for (int s2 = 64; s2 >= 1; s2 >>= 1) {
        if (t < s2) red[t] += red[t + s2];
        __syncthreads();
    }
    if (t == 0) out[g] = red[0] + ob[0];
}

extern "C" void kernel_launch(void* const* d_in, const int* in_sizes, int n_in,
                              void* d_out, int out_size, void* d_ws, size_t ws_size,
                              hipStream_t stream) {
    const float* af   = (const float*)d_in[0];
    const float* bond = (const float*)d_in[1];
    const int*   src  = (const int*)d_in[2];
    const int*   dst  = (const int*)d_in[3];
    const int*   gid  = (const int*)d_in[4];
    const float* embW = (const float*)d_in[5];
    const float* embB = (const float*)d_in[6];
    const float* Wi   = (const float*)d_in[7];
    const float* gi   = (const float*)d_in[9];
    const float* bbi  = (const float*)d_in[10];
    const float* Wu   = (const float*)d_in[11];
    const float* gu   = (const float*)d_in[13];
    const float* bbu  = (const float*)d_in[14];
    const float* gn   = (const float*)d_in[15];
    const float* bbn  = (const float*)d_in[16];
    const float* fcW  = (const float*)d_in[17];
    const float* fcb  = (const float*)d_in[18];
    const float* oW   = (const float*)d_in[19];
    const float* ob   = (const float*)d_in[20];
    float* out = (float*)d_out;

    char* ws = (char*)d_ws;
    size_t off = 0;
    auto take = [&](size_t bytes) {
        size_t o = off;
        off += (bytes + 255) & ~(size_t)255;
        return o;
    };
    float* h     = (float*)(ws + take((size_t)NN * DD * 4));
    float* m     = (float*)(ws + take((size_t)NN * DD * 4));
    float* stats = (float*)(ws + take(512 * 4));
    float* coeff = (float*)(ws + take(512 * 4)); // [sI,tI,sU,tU | sN,tN]
    float* pq    = (float*)(ws + take((size_t)2 * 64 * NBLK * 4)); // 2.56 MB partial sumsq
    float* mpart = (float*)(ws + take((size_t)128 * NAB * 4));     // 640 KB m-stat partials
    float* zpart = (float*)(ws + take((size_t)128 * NHB * 4));     // 320 KB zsum partials
    float* pool  = (float*)(ws + take((size_t)NG * DD * 4)); // 32768 B
    float* pcnt  = (float*)(ws + take((size_t)NG * 4));      // 512 B padded
    int* ecount  = (int*)(ws + take((size_t)NN * 4));        // indeg
    int* ocount  = (int*)(ws + take((size_t)NN * 4));        // outdeg (contiguous after ecount)
    int* eoff    = (int*)(ws + take((size_t)(NN + 1) * 4));
    int* ecur    = (int*)(ws + take((size_t)NN * 4));
    int* ssrc    = (int*)(ws + take((size_t)NE * 4));
    int* sdst    = (int*)(ws + take((size_t)NE * 4));
    float* bond_s = (float*)(ws + take((size_t)NE * 4));
    unsigned short* hb    = (unsigned short*)(ws + take((size_t)NN * DD * 2));
    unsigned short* preIb = (unsigned short*)(ws + take((size_t)NE * DD * 2));
    unsigned short* preUb = (unsigned short*)(ws + take((size_t)NE * DD * 2));
    unsigned short* Wf    = (unsigned short*)(ws + take((size_t)6 * 10240 * 2));

    // zero: pool+pcnt (contiguous), ecount+ocount (contiguous), stats
    hipMemsetAsync((void*)pool, 0, 32768 + 512, stream);
    hipMemsetAsync((void*)ecount, 0, 2 * (((size_t)NN * 4 + 255) & ~(size_t)255), stream);
    hipMemsetAsync((void*)stats, 0, 512 * 4, stream);

    prep_wf_k<<<6, 256, 0, stream>>>(Wi, Wu, Wf);
    embed_k<<<(NN + 255) / 256, 256, 0, stream>>>(af, embW, embB, h, hb);

    cnt_edges_k<<<(NE + 255) / 256, 256, 0, stream>>>(src, dst, ecount, ocount);
    csr_scan_k<<<1, 1024, 0, stream>>>(ecount, eoff, ecur);
    fill_edges_k<<<(NE + 255) / 256, 256, 0, stream>>>(src, dst, bond, ecur, ssrc, sdst, bond_s);
    rbfsum_k<<<512, 256, 0, stream>>>(bond, stats + 384);
    zsum_node_k<<<128, 256, 0, stream>>>(hb, ocount, ecount, stats + 256, stats + 320);

    for (int l = 0; l < 3; ++l) {
        const unsigned short* Wfl = Wf + (size_t)l * 2 * 10240;
        edge_pre2_k<<<2 * NBLK, 256, 0, stream>>>(hb, bond_s, Wfl, ssrc, sdst, preIb, preUb, pq);
        red_k<<<128, 256, 0, stream>>>(pq, stats, NBLK);
        fin_iu_k<<<1, 64, 0, stream>>>(stats, Wfl, gi + l * DD, bbi + l * DD,
                                       gu + l * DD, bbu + l * DD, coeff);
        apply_node_k<<<NAB, 256, 0, stream>>>(preIb, preUb, eoff, coeff, m, mpart);
        red_k<<<128, 256, 0, stream>>>(mpart, stats + 128, NAB);
        fin_n_k<<<1, 64, 0, stream>>>(stats, gn + l * DD, bbn + l * DD, coeff + 256);
        h_update_k<<<NHB, 256, 0, stream>>>(h, hb, m, coeff + 256, ocount, ecount,
                                            gid, pool, pcnt, zpart, l == 2 ? 1 : 0);
        if (l < 2) red_k<<<128, 256, 0, stream>>>(zpart, stats + 256, NHB);
    }

    head_k<<<NG, 128, 0, stream>>>(pool, pcnt, fcW, fcb, oW, ob, out);
}

// Round 9
// 616.420 us; speedup vs baseline: 2.2670x; 1.1523x over previous
//
#include <hip/hip_runtime.h>
#include <hip/hip_bf16.h>
#include <math.h>

#define NN 20000
#define NE 320000
#define NG 128
#define DD 64
#define FA 92
#define FF 128
#define NT (NE / 16)          // 16-edge MFMA tiles = 20000
#define NBLK 5000             // blocks per gate in edge_pre2 (1 tile per wave)
#define NAB 1250              // apply_node blocks
#define NHB 625               // h_update blocks (NN*DD/8/256)
#define GAMMA 3.875f          // 31/8
#define CEN (8.0f / 31.0f)    // center spacing

typedef __attribute__((ext_vector_type(8))) short bf16x8;
typedef __attribute__((ext_vector_type(4))) float f32x4;

// stats layout (floats): [0]=qI, [64]=qU, [128]=msum, [192]=msq, [256]=zsumS, [320]=zsumD, [384]=zsumR(32)

__device__ __forceinline__ float sp_(float x) {
    return fmaxf(x, 0.f) + __logf(1.f + __expf(-fabsf(x)));
}
__device__ __forceinline__ float sig_(float x) {
    return 1.f / (1.f + __expf(-x));
}
__device__ __forceinline__ unsigned short f2b(float x) {
    __hip_bfloat16 b = __float2bfloat16(x);
    return *reinterpret_cast<unsigned short*>(&b);
}
__device__ __forceinline__ float b2f(unsigned short u) {
    return __uint_as_float((unsigned)u << 16);
}

// ---------------- embedding: h = af @ emb_W + emb_b (fp32 + bf16 copy) ----------------
__global__ __launch_bounds__(256) void embed_k(const float* __restrict__ af,
                                               const float* __restrict__ W,
                                               const float* __restrict__ b,
                                               float* __restrict__ h,
                                               unsigned short* __restrict__ hb) {
    __shared__ float Ws[FA * DD];
    for (int i = threadIdx.x * 4; i < FA * DD; i += 256 * 4)
        *(float4*)&Ws[i] = *(const float4*)&W[i];
    __syncthreads();
    int n = blockIdx.x * 256 + threadIdx.x;
    if (n >= NN) return;
    float acc[DD];
#pragma unroll
    for (int j = 0; j < DD; ++j) acc[j] = b[j];
    const float* row = af + (size_t)n * FA;
#pragma unroll 1
    for (int k4 = 0; k4 < FA / 4; ++k4) {
        float4 z = *(const float4*)(row + k4 * 4);
#pragma unroll
        for (int kk = 0; kk < 4; ++kk) {
            float a = ((const float*)&z)[kk];
            const float* wr = &Ws[(k4 * 4 + kk) * DD];
#pragma unroll
            for (int j = 0; j < DD; j += 4) {
                float4 w = *(const float4*)(wr + j);
                acc[j + 0] += a * w.x; acc[j + 1] += a * w.y;
                acc[j + 2] += a * w.z; acc[j + 3] += a * w.w;
            }
        }
    }
    float* o = h + (size_t)n * DD;
    unsigned short* ob = hb + (size_t)n * DD;
#pragma unroll
    for (int j = 0; j < DD; j += 4) {
        float4 v; v.x = acc[j]; v.y = acc[j + 1]; v.z = acc[j + 2]; v.w = acc[j + 3];
        *(float4*)(o + j) = v;
    }
#pragma unroll
    for (int j = 0; j < DD; ++j) ob[j] = f2b(acc[j]);
}

// ---------------- weight fragment prep: element = W[kt*32+8c+i][nf*16+r] ----------------
__global__ void prep_wf_k(const float* __restrict__ Wi, const float* __restrict__ Wu,
                          unsigned short* __restrict__ Wf) {
    int b = blockIdx.x;          // 0..5 : layer*2 + gate
    int l = b >> 1, g = b & 1;
    const float* W = (g ? Wu : Wi) + (size_t)l * 160 * DD;
    for (int f = threadIdx.x; f < 10240; f += 256) {
        int i = f & 7;
        int lane = (f >> 3) & 63;
        int nf = (f >> 9) & 3;
        int kt = f >> 11;
        int k = kt * 32 + 8 * (lane >> 4) + i;
        int col = nf * 16 + (lane & 15);
        Wf[(size_t)b * 10240 + f] = f2b(W[k * DD + col]);
    }
}

// ---------------- CSR build (sorted-by-dst edge order) ----------------
__global__ void cnt_edges_k(const int* __restrict__ src, const int* __restrict__ dst,
                            int* __restrict__ icnt, int* __restrict__ ocnt) {
    int e = blockIdx.x * 256 + threadIdx.x;
    if (e < NE) {
        atomicAdd(&icnt[dst[e]], 1);
        atomicAdd(&ocnt[src[e]], 1);
    }
}

__global__ __launch_bounds__(1024) void csr_scan_k(const int* __restrict__ cnt,
                                                   int* __restrict__ off,
                                                   int* __restrict__ cur) {
    __shared__ int part[1024];
    int t = threadIdx.x;
    int base = t * 20;
    int s = 0;
    for (int i = 0; i < 20; ++i) { int idx = base + i; if (idx < NN) s += cnt[idx]; }
    part[t] = s;
    __syncthreads();
    for (int ofs = 1; ofs < 1024; ofs <<= 1) {
        int v = (t >= ofs) ? part[t - ofs] : 0;
        __syncthreads();
        part[t] += v;
        __syncthreads();
    }
    int run = (t == 0) ? 0 : part[t - 1];
    for (int i = 0; i < 20; ++i) {
        int idx = base + i;
        if (idx < NN) { off[idx] = run; cur[idx] = run; run += cnt[idx]; }
    }
    if (t == 1023) off[NN] = run;
}

__global__ void fill_edges_k(const int* __restrict__ src, const int* __restrict__ dst,
                             const float* __restrict__ bond,
                             int* __restrict__ cur, int* __restrict__ ssrc,
                             int* __restrict__ sdst, float* __restrict__ bond_s) {
    int e = blockIdx.x * 256 + threadIdx.x;
    if (e < NE) {
        int d = dst[e];
        int p = atomicAdd(&cur[d], 1);
        ssrc[p] = src[e];
        sdst[p] = d;
        bond_s[p] = bond[e];
    }
}

// ---------------- one-time: column sum of bf16-rounded rbf over all edges ----------------
__global__ __launch_bounds__(256) void rbfsum_k(const float* __restrict__ bond,
                                                float* __restrict__ zr) {
    __shared__ float part[4][32];
    int lane = threadIdx.x & 63;
    int w = threadIdx.x >> 6;
    int col = lane & 31;
    int half = lane >> 5;
    int slot = (blockIdx.x * 4 + w) * 2 + half;
    int nslots = gridDim.x * 8;
    float cen = (float)col * CEN;
    float a = 0.f;
    for (int e = slot; e < NE; e += nslots) {
        float u = bond[e] - cen;
        a += b2f(f2b(__expf(-GAMMA * u * u)));
    }
    a += __shfl_xor(a, 32, 64);
    if (half == 0) part[w][col] = a;
    __syncthreads();
    if (threadIdx.x < 32) {
        float s = part[0][threadIdx.x] + part[1][threadIdx.x] +
                  part[2][threadIdx.x] + part[3][threadIdx.x];
        unsafeAtomicAdd(&zr[threadIdx.x], s);
    }
}

// ---------------- layer 0 only: degree-weighted column sums of hb ----------------
__global__ __launch_bounds__(256) void zsum_node_k(const unsigned short* __restrict__ hb,
                                                   const int* __restrict__ ocnt,
                                                   const int* __restrict__ icnt,
                                                   float* __restrict__ zS,
                                                   float* __restrict__ zD) {
    int t = blockIdx.x * 256 + threadIdx.x;
    int col = t & 63;
    int n0 = t >> 6;
    int nstride = (gridDim.x * 256) >> 6;
    float aS = 0.f, aD = 0.f;
    for (int n = n0; n < NN; n += nstride) {
        float v = b2f(hb[(size_t)n * DD + col]);
        aS += (float)ocnt[n] * v;
        aD += (float)icnt[n] * v;
    }
    unsafeAtomicAdd(&zS[col], aS);
    unsafeAtomicAdd(&zD[col], aD);
}

// ---------------- gather-GEMM, gate-split, 1 tile/wave: pre (bf16) + per-block sumsq ----------------
__global__ __launch_bounds__(256) void edge_pre2_k(const unsigned short* __restrict__ hb,
                                                   const float* __restrict__ bond_s,
                                                   const unsigned short* __restrict__ Wf, // layer base [2][10240]
                                                   const int* __restrict__ ssrc,
                                                   const int* __restrict__ sdst,
                                                   unsigned short* __restrict__ preIb,
                                                   unsigned short* __restrict__ preUb,
                                                   float* __restrict__ pq) {
    __shared__ bf16x8 WfS[1280];     // 20 KB : this gate's fragments
    __shared__ float qred_s[4][64];
    const int g = blockIdx.x & 1;
    const int bidx = blockIdx.x >> 1;       // 0..NBLK-1
    const int lane = threadIdx.x & 63;
    const int w = threadIdx.x >> 6;
    const int r = lane & 15;   // edge-within-tile
    const int c = lane >> 4;   // k-chunk / output col group
    const int tile = bidx * 4 + w;          // exactly NT tiles per gate
    const int e = tile * 16 + r;

    // issue index loads + gathers before staging so they overlap the LDS fill
    int es = ssrc[e];
    int ed = sdst[e];
    float bd = bond_s[e];
    bf16x8 a0 = *(const bf16x8*)(hb + (size_t)es * DD + c * 8);
    bf16x8 a1 = *(const bf16x8*)(hb + (size_t)es * DD + 32 + c * 8);
    bf16x8 a2 = *(const bf16x8*)(hb + (size_t)ed * DD + c * 8);
    bf16x8 a3 = *(const bf16x8*)(hb + (size_t)ed * DD + 32 + c * 8);
    bf16x8 a4;
#pragma unroll
    for (int i = 0; i < 8; ++i) {
        float cen = (float)(8 * c + i) * CEN;
        float u = bd - cen;
        a4[i] = (short)f2b(__expf(-GAMMA * u * u));
    }

    {
        const bf16x8* Wf8 = (const bf16x8*)Wf + (size_t)g * 1280;
        for (int i = threadIdx.x; i < 1280; i += 256) WfS[i] = Wf8[i];
    }
    __syncthreads();

    f32x4 acc[4];
#pragma unroll
    for (int nf = 0; nf < 4; ++nf) {
        f32x4 z4 = {0.f, 0.f, 0.f, 0.f};
        acc[nf] = z4;
    }
#pragma unroll
    for (int kt = 0; kt < 5; ++kt) {
        bf16x8 a = (kt == 0) ? a0 : (kt == 1) ? a1 : (kt == 2) ? a2 : (kt == 3) ? a3 : a4;
#pragma unroll
        for (int nf = 0; nf < 4; ++nf) {
            // swapped operands: A = W^T fragment, B = z fragment  =>  D[outcol][edge]
            acc[nf] = __builtin_amdgcn_mfma_f32_16x16x32_bf16(WfS[(kt * 4 + nf) * 64 + lane], a, acc[nf], 0, 0, 0);
        }
    }

    unsigned short* pre = (g ? preUb : preIb) + (size_t)e * DD + c * 4;
    float q[16];
#pragma unroll
    for (int nf = 0; nf < 4; ++nf) {
        ushort4 o;
        o.x = f2b(acc[nf][0]); o.y = f2b(acc[nf][1]);
        o.z = f2b(acc[nf][2]); o.w = f2b(acc[nf][3]);
        *(ushort4*)(pre + nf * 16) = o;
#pragma unroll
        for (int j = 0; j < 4; ++j)
            q[nf * 4 + j] = acc[nf][j] * acc[nf][j];
    }

    // reduce sumsq across the 16 r-lanes of each c-group
    float vq = 0.f;
#pragma unroll
    for (int s = 0; s < 16; ++s) {
        float a = q[s];
        a += __shfl_xor(a, 1, 64); a += __shfl_xor(a, 2, 64);
        a += __shfl_xor(a, 4, 64); a += __shfl_xor(a, 8, 64);
        if (r == s) vq = a;
    }
    int col = (r >> 2) * 16 + c * 4 + (r & 3);
    qred_s[w][col] = vq;
    __syncthreads();
    if (w == 0) {
        float s4 = qred_s[0][lane] + qred_s[1][lane] + qred_s[2][lane] + qred_s[3][lane];
        pq[((size_t)g * 64 + lane) * NBLK + bidx] = s4;  // per-block partial, no atomics
    }
}

// ---------------- generic row reduce: out[row] = sum(part[row][0..len)) ----------------
__global__ __launch_bounds__(256) void red_k(const float* __restrict__ part,
                                             float* __restrict__ out, int len) {
    __shared__ float red[256];
    const float* row = part + (size_t)blockIdx.x * len;
    float s = 0.f;
    for (int i = threadIdx.x; i < len; i += 256) s += row[i];
    red[threadIdx.x] = s;
    __syncthreads();
    for (int ofs = 128; ofs >= 1; ofs >>= 1) {
        if (threadIdx.x < ofs) red[threadIdx.x] += red[threadIdx.x + ofs];
        __syncthreads();
    }
    if (threadIdx.x == 0) out[blockIdx.x] = red[0];
}

// ---------------- BN coeffs for gate/update: mean via linearity, var via sumsq ----------------
__global__ void fin_iu_k(const float* __restrict__ stats,
                         const unsigned short* __restrict__ Wf, // layer base [2][10240]
                         const float* __restrict__ gi, const float* __restrict__ bbi,
                         const float* __restrict__ gu, const float* __restrict__ bbu,
                         float* __restrict__ coeff) {
    int j = threadIdx.x; // 64 = out col
    int nf = j >> 4, rr = j & 15;
    float muI = 0.f, muU = 0.f;
    for (int k = 0; k < 160; ++k) {
        float zs = (k < 64) ? stats[256 + k] : (k < 128) ? stats[320 + k - 64] : stats[384 + k - 128];
        int kt = k >> 5, rem = k & 31, cc = rem >> 3, ii = rem & 7;
        int f = kt * 2048 + nf * 512 + (cc * 16 + rr) * 8 + ii;
        muI += zs * b2f(Wf[f]);
        muU += zs * b2f(Wf[10240 + f]);
    }
    const float invE = 1.f / (float)NE;
    muI *= invE; muU *= invE;
    float varI = stats[j] * invE - muI * muI;
    float sI = gi[j] * rsqrtf(varI + 1e-5f);
    coeff[j] = sI;
    coeff[64 + j] = bbi[j] - muI * sI;
    float varU = stats[64 + j] * invE - muU * muU;
    float sU = gu[j] * rsqrtf(varU + 1e-5f);
    coeff[128 + j] = sU;
    coeff[192 + j] = bbu[j] - muU * sU;
}

// ---------------- node-parallel apply + fused m column stats (per-block partials) ----------------
__global__ __launch_bounds__(256) void apply_node_k(const unsigned short* __restrict__ preIb,
                                                    const unsigned short* __restrict__ preUb,
                                                    const int* __restrict__ eoff,
                                                    const float* __restrict__ coeff,
                                                    float* __restrict__ m,
                                                    float* __restrict__ mpart) {
    __shared__ float ps[256][4];
    __shared__ float pq2[256][4];
    int t = blockIdx.x * 256 + threadIdx.x; // NN*16 threads exactly
    int chunk = t & 15;
    int n = t >> 4;
    float sIv[4], tIv[4], sUv[4], tUv[4];
#pragma unroll
    for (int q = 0; q < 4; ++q) {
        int col = chunk * 4 + q;
        sIv[q] = coeff[col];       tIv[q] = coeff[64 + col];
        sUv[q] = coeff[128 + col]; tUv[q] = coeff[192 + col];
    }
    int b = eoff[n], e = eoff[n + 1];
    float acc[4] = {0.f, 0.f, 0.f, 0.f};
    for (int p = b; p < e; ++p) {
        ushort4 vi = *(const ushort4*)(preIb + (size_t)p * DD + chunk * 4);
        ushort4 vu = *(const ushort4*)(preUb + (size_t)p * DD + chunk * 4);
        acc[0] += sig_(b2f(vi.x) * sIv[0] + tIv[0]) * sp_(b2f(vu.x) * sUv[0] + tUv[0]);
        acc[1] += sig_(b2f(vi.y) * sIv[1] + tIv[1]) * sp_(b2f(vu.y) * sUv[1] + tUv[1]);
        acc[2] += sig_(b2f(vi.z) * sIv[2] + tIv[2]) * sp_(b2f(vu.z) * sUv[2] + tUv[2]);
        acc[3] += sig_(b2f(vi.w) * sIv[3] + tIv[3]) * sp_(b2f(vu.w) * sUv[3] + tUv[3]);
    }
    float4 v; v.x = acc[0]; v.y = acc[1]; v.z = acc[2]; v.w = acc[3];
    *(float4*)(m + (size_t)n * DD + chunk * 4) = v;
#pragma unroll
    for (int q = 0; q < 4; ++q) {
        ps[threadIdx.x][q] = acc[q];
        pq2[threadIdx.x][q] = acc[q] * acc[q];
    }
    __syncthreads();
    if (threadIdx.x < 64) {
        int cc = threadIdx.x;
        int ch = cc >> 2, qq = cc & 3;
        float s = 0.f, q2 = 0.f;
#pragma unroll
        for (int nn = 0; nn < 16; ++nn) {
            s += ps[nn * 16 + ch][qq];
            q2 += pq2[nn * 16 + ch][qq];
        }
        mpart[(size_t)cc * NAB + blockIdx.x] = s;
        mpart[(size_t)(64 + cc) * NAB + blockIdx.x] = q2;
    }
}

// ---------------- finalize BN(m) ----------------
__global__ void fin_n_k(const float* __restrict__ stats,
                        const float* __restrict__ gn, const float* __restrict__ bbn,
                        float* __restrict__ coeffN) {
    int j = threadIdx.x; // 64
    const float invN = 1.f / (float)NN;
    float mu = stats[128 + j] * invN;
    float var = stats[192 + j] * invN - mu * mu;
    float s = gn[j] * rsqrtf(var + 1e-5f);
    coeffN[j] = s;
    coeffN[64 + j] = bbn[j] - mu * s;
}

// ---------------- h = sp(h + bn(m)), 8-wide; non-fin fuses next-layer zsum partials ----------------
__global__ __launch_bounds__(256) void h_update_k(float* __restrict__ h,
                                                  unsigned short* __restrict__ hb,
                                                  const float* __restrict__ m,
                                                  const float* __restrict__ coeffN,
                                                  const int* __restrict__ ocnt,
                                                  const int* __restrict__ icnt,
                                                  float* __restrict__ zpart,
                                                  int fin) {
    __shared__ float wzs[4][8][8], wzd[4][8][8];
    int t = blockIdx.x * 256 + threadIdx.x;  // NN*DD/8 = 160000 threads exactly
    int n = t >> 3, ch = t & 7;
    int base = n * DD + ch * 8;
    float4 m0 = *(const float4*)(m + base);
    float4 m1 = *(const float4*)(m + base + 4);
    float4 h0 = *(const float4*)(h + base);
    float4 h1 = *(const float4*)(h + base + 4);
    float mv[8] = {m0.x, m0.y, m0.z, m0.w, m1.x, m1.y, m1.z, m1.w};
    float hv[8] = {h0.x, h0.y, h0.z, h0.w, h1.x, h1.y, h1.z, h1.w};
    unsigned short hbv[8];
#pragma unroll
    for (int q = 0; q < 8; ++q) {
        int col = ch * 8 + q;
        float v = sp_(hv[q] + mv[q] * coeffN[col] + coeffN[64 + col]);
        hv[q] = v;
        hbv[q] = f2b(v);
    }
    float4 o0, o1;
    o0.x = hv[0]; o0.y = hv[1]; o0.z = hv[2]; o0.w = hv[3];
    o1.x = hv[4]; o1.y = hv[5]; o1.z = hv[6]; o1.w = hv[7];
    *(float4*)(h + base) = o0;
    *(float4*)(h + base + 4) = o1;
    if (fin) return;  // pooling handled by pool_seg_k from h

    bf16x8 hb8;
#pragma unroll
    for (int q = 0; q < 8; ++q) hb8[q] = (short)hbv[q];
    *(bf16x8*)(hb + base) = hb8;

    // fused zsum partials for next layer: rows use the bf16-ROUNDED values
    float oc = (float)ocnt[n], ic = (float)icnt[n];
    float zs8[8], zd8[8];
#pragma unroll
    for (int q = 0; q < 8; ++q) {
        float r = b2f(hbv[q]);
        zs8[q] = r * oc;
        zd8[q] = r * ic;
    }
    // reduce over the 8 node-rows within each wave (lane = nrow*8 + ch)
#pragma unroll
    for (int mk = 8; mk <= 32; mk <<= 1) {
#pragma unroll
        for (int q = 0; q < 8; ++q) {
            zs8[q] += __shfl_xor(zs8[q], mk, 64);
            zd8[q] += __shfl_xor(zd8[q], mk, 64);
        }
    }
    int lane = threadIdx.x & 63;
    int w = threadIdx.x >> 6;
    if (lane < 8) {
#pragma unroll
        for (int q = 0; q < 8; ++q) {
            wzs[w][lane][q] = zs8[q];
            wzd[w][lane][q] = zd8[q];
        }
    }
    __syncthreads();
    if (threadIdx.x < 64) {
        int chh = threadIdx.x >> 3, qq = threadIdx.x & 7; // col = chh*8+qq = threadIdx.x
        float s = wzs[0][chh][qq] + wzs[1][chh][qq] + wzs[2][chh][qq] + wzs[3][chh][qq];
        float d = wzd[0][chh][qq] + wzd[1][chh][qq] + wzd[2][chh][qq] + wzd[3][chh][qq];
        zpart[(size_t)threadIdx.x * NHB + blockIdx.x] = s;
        zpart[(size_t)(64 + threadIdx.x) * NHB + blockIdx.x] = d;
    }
}

// ---------------- segmented pooling over sorted gid: no atomics ----------------
__global__ __launch_bounds__(256) void pool_seg_k(const float* __restrict__ h,
                                                  const int* __restrict__ gid,
                                                  float* __restrict__ pool,
                                                  float* __restrict__ pcnt) {
    __shared__ int s_lo, s_hi;
    __shared__ float red[4][DD];
    int g = blockIdx.x;
    if (threadIdx.x == 0) {
        int lo = 0, hi = NN;
        while (lo < hi) { int mid = (lo + hi) >> 1; if (gid[mid] < g) lo = mid + 1; else hi = mid; }
        s_lo = lo;
        int lo2 = lo, hi2 = NN;
        while (lo2 < hi2) { int mid = (lo2 + hi2) >> 1; if (gid[mid] < g + 1) lo2 = mid + 1; else hi2 = mid; }
        s_hi = lo2;
    }
    __syncthreads();
    int lo = s_lo, hi = s_hi;
    int col = threadIdx.x & 63;
    int rr = threadIdx.x >> 6;
    float s = 0.f;
    for (int n = lo + rr; n < hi; n += 4) s += h[(size_t)n * DD + col];
    red[rr][col] = s;
    __syncthreads();
    if (threadIdx.x < 64) {
        float v = red[0][col] + red[1][col] + red[2][col] + red[3][col];
        pool[(size_t)g * DD + col] = v;
        if (col == 0) pcnt[g] = (float)(hi - lo);
    }
}

// ---------------- head ----------------
__global__ __launch_bounds__(128) void head_k(const float* __restrict__ pool,
                                              const float* __restrict__ pcnt,
                                              const float* __restrict__ fcW,
                                              const float* __restrict__ fcb,
                                              const float* __restrict__ oW,
                                              const float* __restrict__ ob,
                                              float* __restrict__ out) {
    int g = blockIdx.x;
    int t = threadIdx.x; // 128
    __shared__ float feats[DD];
    __shared__ float red[FF];
    if (t < DD) {
        float c = fmaxf(pcnt[g], 1.f);
        feats[t] = sp_(pool[(size_t)g * DD + t] / c);
    }
    __syncthreads();
    float a = fcb[t];
#pragma unroll 1
    for (int j = 0; j < DD; ++j) a += feats[j] * fcW[j * FF + t];
    float y = sp_(sp_(a));
    red[t] = y * oW[t];
    __syncthreads();
    for (int s2 = 64; s2 >= 1; s2 >>= 1) {
        if (t < s2) red[t] += red[t + s2];
        __syncthreads();
    }
    if (t == 0) out[g] = red[0] + ob[0];
}

extern "C" void kernel_launch(void* const* d_in, const int* in_sizes, int n_in,
                              void* d_out, int out_size, void* d_ws, size_t ws_size,
                              hipStream_t stream) {
    const float* af   = (const float*)d_in[0];
    const float* bond = (const float*)d_in[1];
    const int*   src  = (const int*)d_in[2];
    const int*   dst  = (const int*)d_in[3];
    const int*   gid  = (const int*)d_in[4];
    const float* embW = (const float*)d_in[5];
    const float* embB = (const float*)d_in[6];
    const float* Wi   = (const float*)d_in[7];
    const float* gi   = (const float*)d_in[9];
    const float* bbi  = (const float*)d_in[10];
    const float* Wu   = (const float*)d_in[11];
    const float* gu   = (const float*)d_in[13];
    const float* bbu  = (const float*)d_in[14];
    const float* gn   = (const float*)d_in[15];
    const float* bbn  = (const float*)d_in[16];
    const float* fcW  = (const float*)d_in[17];
    const float* fcb  = (const float*)d_in[18];
    const float* oW   = (const float*)d_in[19];
    const float* ob   = (const float*)d_in[20];
    float* out = (float*)d_out;

    char* ws = (char*)d_ws;
    size_t off = 0;
    auto take = [&](size_t bytes) {
        size_t o = off;
        off += (bytes + 255) & ~(size_t)255;
        return o;
    };
    float* h     = (float*)(ws + take((size_t)NN * DD * 4));
    float* m     = (float*)(ws + take((size_t)NN * DD * 4));
    float* stats = (float*)(ws + take(512 * 4));
    float* coeff = (float*)(ws + take(512 * 4)); // [sI,tI,sU,tU | sN,tN]
    float* pq    = (float*)(ws + take((size_t)2 * 64 * NBLK * 4)); // 2.56 MB partial sumsq
    float* mpart = (float*)(ws + take((size_t)128 * NAB * 4));     // 640 KB m-stat partials
    float* zpart = (float*)(ws + take((size_t)128 * NHB * 4));     // 320 KB zsum partials
    float* pool  = (float*)(ws + take((size_t)NG * DD * 4)); // 32768 B
    float* pcnt  = (float*)(ws + take((size_t)NG * 4));
    int* ecount  = (int*)(ws + take((size_t)NN * 4));        // indeg
    int* ocount  = (int*)(ws + take((size_t)NN * 4));        // outdeg (contiguous after ecount)
    int* eoff    = (int*)(ws + take((size_t)(NN + 1) * 4));
    int* ecur    = (int*)(ws + take((size_t)NN * 4));
    int* ssrc    = (int*)(ws + take((size_t)NE * 4));
    int* sdst    = (int*)(ws + take((size_t)NE * 4));
    float* bond_s = (float*)(ws + take((size_t)NE * 4));
    unsigned short* hb    = (unsigned short*)(ws + take((size_t)NN * DD * 2));
    unsigned short* preIb = (unsigned short*)(ws + take((size_t)NE * DD * 2));
    unsigned short* preUb = (unsigned short*)(ws + take((size_t)NE * DD * 2));
    unsigned short* Wf    = (unsigned short*)(ws + take((size_t)6 * 10240 * 2));

    // zero: ecount+ocount (contiguous), stats
    hipMemsetAsync((void*)ecount, 0, 2 * (((size_t)NN * 4 + 255) & ~(size_t)255), stream);
    hipMemsetAsync((void*)stats, 0, 512 * 4, stream);

    prep_wf_k<<<6, 256, 0, stream>>>(Wi, Wu, Wf);
    embed_k<<<(NN + 255) / 256, 256, 0, stream>>>(af, embW, embB, h, hb);

    cnt_edges_k<<<(NE + 255) / 256, 256, 0, stream>>>(src, dst, ecount, ocount);
    csr_scan_k<<<1, 1024, 0, stream>>>(ecount, eoff, ecur);
    fill_edges_k<<<(NE + 255) / 256, 256, 0, stream>>>(src, dst, bond, ecur, ssrc, sdst, bond_s);
    rbfsum_k<<<512, 256, 0, stream>>>(bond, stats + 384);
    zsum_node_k<<<128, 256, 0, stream>>>(hb, ocount, ecount, stats + 256, stats + 320);

    for (int l = 0; l < 3; ++l) {
        const unsigned short* Wfl = Wf + (size_t)l * 2 * 10240;
        edge_pre2_k<<<2 * NBLK, 256, 0, stream>>>(hb, bond_s, Wfl, ssrc, sdst, preIb, preUb, pq);
        red_k<<<128, 256, 0, stream>>>(pq, stats, NBLK);
        fin_iu_k<<<1, 64, 0, stream>>>(stats, Wfl, gi + l * DD, bbi + l * DD,
                                       gu + l * DD, bbu + l * DD, coeff);
        apply_node_k<<<NAB, 256, 0, stream>>>(preIb, preUb, eoff, coeff, m, mpart);
        red_k<<<128, 256, 0, stream>>>(mpart, stats + 128, NAB);
        fin_n_k<<<1, 64, 0, stream>>>(stats, gn + l * DD, bbn + l * DD, coeff + 256);
        h_update_k<<<NHB, 256, 0, stream>>>(h, hb, m, coeff + 256, ocount, ecount,
                                            zpart, l == 2 ? 1 : 0);
        if (l < 2) red_k<<<128, 256, 0, stream>>>(zpart, stats + 256, NHB);
    }

    pool_seg_k<<<NG, 256, 0, stream>>>(h, gid, pool, pcnt);
    head_k<<<NG, 128, 0, stream>>>(pool, pcnt, fcW, fcb, oW, ob, out);
}

// Round 10
// 554.954 us; speedup vs baseline: 2.5181x; 1.1108x over previous
//
#include <hip/hip_runtime.h>
#include <hip/hip_bf16.h>
#include <math.h>

#define NN 20000
#define NE 320000
#define NG 128
#define DD 64
#define FA 92
#define FF 128
#define NT (NE / 16)          // 16-edge MFMA tiles = 20000
#define NBLK 5000             // blocks per gate in edge_pre2 (1 tile per wave)
#define NAB 2500              // apply_node blocks (32 threads/node)
#define NHB 625               // h_update blocks (NN*DD/8/256)
#define GAMMA 3.875f          // 31/8
#define CEN (8.0f / 31.0f)    // center spacing

typedef __attribute__((ext_vector_type(8))) short bf16x8;
typedef __attribute__((ext_vector_type(4))) float f32x4;

// stats layout (floats): [0]=qI, [64]=qU, [128]=msum, [192]=msq, [256]=zsumS, [320]=zsumD, [384]=zsumR(32)

__device__ __forceinline__ float sp_(float x) {
    return fmaxf(x, 0.f) + __logf(1.f + __expf(-fabsf(x)));
}
__device__ __forceinline__ float sig_(float x) {
    return 1.f / (1.f + __expf(-x));
}
__device__ __forceinline__ unsigned short f2b(float x) {
    __hip_bfloat16 b = __float2bfloat16(x);
    return *reinterpret_cast<unsigned short*>(&b);
}
__device__ __forceinline__ float b2f(unsigned short u) {
    return __uint_as_float((unsigned)u << 16);
}

// ---------------- embedding: h = af @ emb_W + emb_b ; 8 threads/node ----------------
__global__ __launch_bounds__(256) void embed_k(const float* __restrict__ af,
                                               const float* __restrict__ W,
                                               const float* __restrict__ b,
                                               float* __restrict__ h,
                                               unsigned short* __restrict__ hb) {
    __shared__ float Ws[FA * DD];   // 23552 B
    __shared__ float afS[32][FA];   // 11776 B
    const int n0 = blockIdx.x * 32;
    for (int i = threadIdx.x * 4; i < FA * DD; i += 256 * 4)
        *(float4*)&Ws[i] = *(const float4*)&W[i];
    const float4* af4 = (const float4*)(af + (size_t)n0 * FA);
    for (int i = threadIdx.x; i < 32 * FA / 4; i += 256) {
        float4 v = af4[i];
        int nl = i / (FA / 4), kk = (i % (FA / 4)) * 4;
        *(float4*)&afS[nl][kk] = v;
    }
    __syncthreads();
    int nl = threadIdx.x >> 3, ch = threadIdx.x & 7;
    int n = n0 + nl;
    float acc[8];
#pragma unroll
    for (int q = 0; q < 8; ++q) acc[q] = b[ch * 8 + q];
#pragma unroll 4
    for (int k = 0; k < FA; ++k) {
        float a = afS[nl][k];
        const float* wr = &Ws[k * DD + ch * 8];
        float4 w0 = *(const float4*)wr;
        float4 w1 = *(const float4*)(wr + 4);
        acc[0] += a * w0.x; acc[1] += a * w0.y; acc[2] += a * w0.z; acc[3] += a * w0.w;
        acc[4] += a * w1.x; acc[5] += a * w1.y; acc[6] += a * w1.z; acc[7] += a * w1.w;
    }
    float* o = h + (size_t)n * DD + ch * 8;
    float4 o0, o1;
    o0.x = acc[0]; o0.y = acc[1]; o0.z = acc[2]; o0.w = acc[3];
    o1.x = acc[4]; o1.y = acc[5]; o1.z = acc[6]; o1.w = acc[7];
    *(float4*)o = o0;
    *(float4*)(o + 4) = o1;
    bf16x8 hb8;
#pragma unroll
    for (int q = 0; q < 8; ++q) hb8[q] = (short)f2b(acc[q]);
    *(bf16x8*)(hb + (size_t)n * DD + ch * 8) = hb8;
}

// ---------------- weight fragment prep: element = W[kt*32+8c+i][nf*16+r] ----------------
__global__ void prep_wf_k(const float* __restrict__ Wi, const float* __restrict__ Wu,
                          unsigned short* __restrict__ Wf) {
    int b = blockIdx.x;          // 0..5 : layer*2 + gate
    int l = b >> 1, g = b & 1;
    const float* W = (g ? Wu : Wi) + (size_t)l * 160 * DD;
    for (int f = threadIdx.x; f < 10240; f += 256) {
        int i = f & 7;
        int lane = (f >> 3) & 63;
        int nf = (f >> 9) & 3;
        int kt = f >> 11;
        int k = kt * 32 + 8 * (lane >> 4) + i;
        int col = nf * 16 + (lane & 15);
        Wf[(size_t)b * 10240 + f] = f2b(W[k * DD + col]);
    }
}

// ---------------- CSR build (sorted-by-dst edge order) ----------------
__global__ void cnt_edges_k(const int* __restrict__ src, const int* __restrict__ dst,
                            int* __restrict__ icnt, int* __restrict__ ocnt) {
    int e = blockIdx.x * 256 + threadIdx.x;
    if (e < NE) {
        atomicAdd(&icnt[dst[e]], 1);
        atomicAdd(&ocnt[src[e]], 1);
    }
}

__global__ __launch_bounds__(1024) void csr_scan_k(const int* __restrict__ cnt,
                                                   int* __restrict__ off,
                                                   int* __restrict__ cur) {
    __shared__ int part[1024];
    int t = threadIdx.x;
    int base = t * 20;
    int s = 0;
    for (int i = 0; i < 20; ++i) { int idx = base + i; if (idx < NN) s += cnt[idx]; }
    part[t] = s;
    __syncthreads();
    for (int ofs = 1; ofs < 1024; ofs <<= 1) {
        int v = (t >= ofs) ? part[t - ofs] : 0;
        __syncthreads();
        part[t] += v;
        __syncthreads();
    }
    int run = (t == 0) ? 0 : part[t - 1];
    for (int i = 0; i < 20; ++i) {
        int idx = base + i;
        if (idx < NN) { off[idx] = run; cur[idx] = run; run += cnt[idx]; }
    }
    if (t == 1023) off[NN] = run;
}

__global__ void fill_edges_k(const int* __restrict__ src, const int* __restrict__ dst,
                             const float* __restrict__ bond,
                             int* __restrict__ cur, int* __restrict__ ssrc,
                             int* __restrict__ sdst, float* __restrict__ bond_s) {
    int e = blockIdx.x * 256 + threadIdx.x;
    if (e < NE) {
        int d = dst[e];
        int p = atomicAdd(&cur[d], 1);
        ssrc[p] = src[e];
        sdst[p] = d;
        bond_s[p] = bond[e];
    }
}

// ---------------- one-time: column sum of bf16-rounded rbf over all edges ----------------
__global__ __launch_bounds__(256) void rbfsum_k(const float* __restrict__ bond,
                                                float* __restrict__ zr) {
    __shared__ float part[4][32];
    int lane = threadIdx.x & 63;
    int w = threadIdx.x >> 6;
    int col = lane & 31;
    int half = lane >> 5;
    int slot = (blockIdx.x * 4 + w) * 2 + half;
    int nslots = gridDim.x * 8;
    float cen = (float)col * CEN;
    float a = 0.f;
    for (int e = slot; e < NE; e += nslots) {
        float u = bond[e] - cen;
        a += b2f(f2b(__expf(-GAMMA * u * u)));
    }
    a += __shfl_xor(a, 32, 64);
    if (half == 0) part[w][col] = a;
    __syncthreads();
    if (threadIdx.x < 32) {
        float s = part[0][threadIdx.x] + part[1][threadIdx.x] +
                  part[2][threadIdx.x] + part[3][threadIdx.x];
        unsafeAtomicAdd(&zr[threadIdx.x], s);
    }
}

// ---------------- layer 0 only: degree-weighted column sums of hb ----------------
__global__ __launch_bounds__(256) void zsum_node_k(const unsigned short* __restrict__ hb,
                                                   const int* __restrict__ ocnt,
                                                   const int* __restrict__ icnt,
                                                   float* __restrict__ zS,
                                                   float* __restrict__ zD) {
    int t = blockIdx.x * 256 + threadIdx.x;
    int col = t & 63;
    int n0 = t >> 6;
    int nstride = (gridDim.x * 256) >> 6;
    float aS = 0.f, aD = 0.f;
    for (int n = n0; n < NN; n += nstride) {
        float v = b2f(hb[(size_t)n * DD + col]);
        aS += (float)ocnt[n] * v;
        aD += (float)icnt[n] * v;
    }
    unsafeAtomicAdd(&zS[col], aS);
    unsafeAtomicAdd(&zD[col], aD);
}

// ---------------- gather-GEMM, gate-split, 1 tile/wave: pre (bf16) + per-block sumsq ----------------
__global__ __launch_bounds__(256) void edge_pre2_k(const unsigned short* __restrict__ hb,
                                                   const float* __restrict__ bond_s,
                                                   const unsigned short* __restrict__ Wf, // layer base [2][10240]
                                                   const int* __restrict__ ssrc,
                                                   const int* __restrict__ sdst,
                                                   unsigned short* __restrict__ preIb,
                                                   unsigned short* __restrict__ preUb,
                                                   float* __restrict__ pq) {
    __shared__ bf16x8 WfS[1280];     // 20 KB : this gate's fragments
    __shared__ float qred_s[4][64];
    const int g = blockIdx.x & 1;
    const int bidx = blockIdx.x >> 1;       // 0..NBLK-1
    const int lane = threadIdx.x & 63;
    const int w = threadIdx.x >> 6;
    const int r = lane & 15;   // edge-within-tile
    const int c = lane >> 4;   // k-chunk / output col group
    const int tile = bidx * 4 + w;          // exactly NT tiles per gate
    const int e = tile * 16 + r;

    // issue index loads + gathers before staging so they overlap the LDS fill
    int es = ssrc[e];
    int ed = sdst[e];
    float bd = bond_s[e];
    bf16x8 a0 = *(const bf16x8*)(hb + (size_t)es * DD + c * 8);
    bf16x8 a1 = *(const bf16x8*)(hb + (size_t)es * DD + 32 + c * 8);
    bf16x8 a2 = *(const bf16x8*)(hb + (size_t)ed * DD + c * 8);
    bf16x8 a3 = *(const bf16x8*)(hb + (size_t)ed * DD + 32 + c * 8);
    bf16x8 a4;
#pragma unroll
    for (int i = 0; i < 8; ++i) {
        float cen = (float)(8 * c + i) * CEN;
        float u = bd - cen;
        a4[i] = (short)f2b(__expf(-GAMMA * u * u));
    }

    {
        const bf16x8* Wf8 = (const bf16x8*)Wf + (size_t)g * 1280;
        for (int i = threadIdx.x; i < 1280; i += 256) WfS[i] = Wf8[i];
    }
    __syncthreads();

    f32x4 acc[4];
#pragma unroll
    for (int nf = 0; nf < 4; ++nf) {
        f32x4 z4 = {0.f, 0.f, 0.f, 0.f};
        acc[nf] = z4;
    }
#pragma unroll
    for (int kt = 0; kt < 5; ++kt) {
        bf16x8 a = (kt == 0) ? a0 : (kt == 1) ? a1 : (kt == 2) ? a2 : (kt == 3) ? a3 : a4;
#pragma unroll
        for (int nf = 0; nf < 4; ++nf) {
            // swapped operands: A = W^T fragment, B = z fragment  =>  D[outcol][edge]
            acc[nf] = __builtin_amdgcn_mfma_f32_16x16x32_bf16(WfS[(kt * 4 + nf) * 64 + lane], a, acc[nf], 0, 0, 0);
        }
    }

    unsigned short* pre = (g ? preUb : preIb) + (size_t)e * DD + c * 4;
    float q[16];
#pragma unroll
    for (int nf = 0; nf < 4; ++nf) {
        ushort4 o;
        o.x = f2b(acc[nf][0]); o.y = f2b(acc[nf][1]);
        o.z = f2b(acc[nf][2]); o.w = f2b(acc[nf][3]);
        *(ushort4*)(pre + nf * 16) = o;
#pragma unroll
        for (int j = 0; j < 4; ++j)
            q[nf * 4 + j] = acc[nf][j] * acc[nf][j];
    }

    // reduce sumsq across the 16 r-lanes of each c-group
    float vq = 0.f;
#pragma unroll
    for (int s = 0; s < 16; ++s) {
        float a = q[s];
        a += __shfl_xor(a, 1, 64); a += __shfl_xor(a, 2, 64);
        a += __shfl_xor(a, 4, 64); a += __shfl_xor(a, 8, 64);
        if (r == s) vq = a;
    }
    int col = (r >> 2) * 16 + c * 4 + (r & 3);
    qred_s[w][col] = vq;
    __syncthreads();
    if (w == 0) {
        float s4 = qred_s[0][lane] + qred_s[1][lane] + qred_s[2][lane] + qred_s[3][lane];
        pq[((size_t)g * 64 + lane) * NBLK + bidx] = s4;  // per-block partial, no atomics
    }
}

// ---------------- generic row reduce: out[row] = sum(part[row][0..len)) ----------------
__global__ __launch_bounds__(256) void red_k(const float* __restrict__ part,
                                             float* __restrict__ out, int len) {
    __shared__ float red[256];
    const float* row = part + (size_t)blockIdx.x * len;
    float s = 0.f;
    for (int i = threadIdx.x; i < len; i += 256) s += row[i];
    red[threadIdx.x] = s;
    __syncthreads();
    for (int ofs = 128; ofs >= 1; ofs >>= 1) {
        if (threadIdx.x < ofs) red[threadIdx.x] += red[threadIdx.x + ofs];
        __syncthreads();
    }
    if (threadIdx.x == 0) out[blockIdx.x] = red[0];
}

// ---------------- BN coeffs for gate/update: mean via linearity, var via sumsq ----------------
__global__ void fin_iu_k(const float* __restrict__ stats,
                         const unsigned short* __restrict__ Wf, // layer base [2][10240]
                         const float* __restrict__ gi, const float* __restrict__ bbi,
                         const float* __restrict__ gu, const float* __restrict__ bbu,
                         float* __restrict__ coeff) {
    int j = threadIdx.x; // 64 = out col
    int nf = j >> 4, rr = j & 15;
    float muI = 0.f, muU = 0.f;
    for (int k = 0; k < 160; ++k) {
        float zs = (k < 64) ? stats[256 + k] : (k < 128) ? stats[320 + k - 64] : stats[384 + k - 128];
        int kt = k >> 5, rem = k & 31, cc = rem >> 3, ii = rem & 7;
        int f = kt * 2048 + nf * 512 + (cc * 16 + rr) * 8 + ii;
        muI += zs * b2f(Wf[f]);
        muU += zs * b2f(Wf[10240 + f]);
    }
    const float invE = 1.f / (float)NE;
    muI *= invE; muU *= invE;
    float varI = stats[j] * invE - muI * muI;
    float sI = gi[j] * rsqrtf(varI + 1e-5f);
    coeff[j] = sI;
    coeff[64 + j] = bbi[j] - muI * sI;
    float varU = stats[64 + j] * invE - muU * muU;
    float sU = gu[j] * rsqrtf(varU + 1e-5f);
    coeff[128 + j] = sU;
    coeff[192 + j] = bbu[j] - muU * sU;
}

// ---------------- node-parallel apply (32 thr/node) + fused m column stats ----------------
__global__ __launch_bounds__(256) void apply_node_k(const unsigned short* __restrict__ preIb,
                                                    const unsigned short* __restrict__ preUb,
                                                    const int* __restrict__ eoff,
                                                    const float* __restrict__ coeff,
                                                    float* __restrict__ m,
                                                    float* __restrict__ mpart) {
    __shared__ float ps[128][4];
    __shared__ float pq2[128][4];
    int t = blockIdx.x * 256 + threadIdx.x; // NN*32 threads exactly
    int chunk = t & 15;
    int half = (t >> 4) & 1;
    int n = t >> 5;
    float sIv[4], tIv[4], sUv[4], tUv[4];
#pragma unroll
    for (int q = 0; q < 4; ++q) {
        int col = chunk * 4 + q;
        sIv[q] = coeff[col];       tIv[q] = coeff[64 + col];
        sUv[q] = coeff[128 + col]; tUv[q] = coeff[192 + col];
    }
    int b = eoff[n], e = eoff[n + 1];
    float acc[4] = {0.f, 0.f, 0.f, 0.f};
    for (int p = b + half; p < e; p += 2) {
        ushort4 vi = *(const ushort4*)(preIb + (size_t)p * DD + chunk * 4);
        ushort4 vu = *(const ushort4*)(preUb + (size_t)p * DD + chunk * 4);
        acc[0] += sig_(b2f(vi.x) * sIv[0] + tIv[0]) * sp_(b2f(vu.x) * sUv[0] + tUv[0]);
        acc[1] += sig_(b2f(vi.y) * sIv[1] + tIv[1]) * sp_(b2f(vu.y) * sUv[1] + tUv[1]);
        acc[2] += sig_(b2f(vi.z) * sIv[2] + tIv[2]) * sp_(b2f(vu.z) * sUv[2] + tUv[2]);
        acc[3] += sig_(b2f(vi.w) * sIv[3] + tIv[3]) * sp_(b2f(vu.w) * sUv[3] + tUv[3]);
    }
    // merge the two half-threads (lanes differ by 16)
#pragma unroll
    for (int q = 0; q < 4; ++q) acc[q] += __shfl_xor(acc[q], 16, 64);
    if (half == 0) {
        float4 v; v.x = acc[0]; v.y = acc[1]; v.z = acc[2]; v.w = acc[3];
        *(float4*)(m + (size_t)n * DD + chunk * 4) = v;
        int idx = ((threadIdx.x >> 5) << 4) | chunk;  // 0..127
#pragma unroll
        for (int q = 0; q < 4; ++q) {
            ps[idx][q] = acc[q];
            pq2[idx][q] = acc[q] * acc[q];
        }
    }
    __syncthreads();
    if (threadIdx.x < 64) {
        int cc = threadIdx.x;
        int ch = cc >> 2, qq = cc & 3;
        float s = 0.f, q2 = 0.f;
#pragma unroll
        for (int nn = 0; nn < 8; ++nn) {
            s += ps[nn * 16 + ch][qq];
            q2 += pq2[nn * 16 + ch][qq];
        }
        mpart[(size_t)cc * NAB + blockIdx.x] = s;
        mpart[(size_t)(64 + cc) * NAB + blockIdx.x] = q2;
    }
}

// ---------------- finalize BN(m) ----------------
__global__ void fin_n_k(const float* __restrict__ stats,
                        const float* __restrict__ gn, const float* __restrict__ bbn,
                        float* __restrict__ coeffN) {
    int j = threadIdx.x; // 64
    const float invN = 1.f / (float)NN;
    float mu = stats[128 + j] * invN;
    float var = stats[192 + j] * invN - mu * mu;
    float s = gn[j] * rsqrtf(var + 1e-5f);
    coeffN[j] = s;
    coeffN[64 + j] = bbn[j] - mu * s;
}

// ---------------- h = sp(h + bn(m)), 8-wide; non-fin fuses next-layer zsum partials ----------------
__global__ __launch_bounds__(256) void h_update_k(float* __restrict__ h,
                                                  unsigned short* __restrict__ hb,
                                                  const float* __restrict__ m,
                                                  const float* __restrict__ coeffN,
                                                  const int* __restrict__ ocnt,
                                                  const int* __restrict__ icnt,
                                                  float* __restrict__ zpart,
                                                  int fin) {
    __shared__ float wzs[4][8][8], wzd[4][8][8];
    int t = blockIdx.x * 256 + threadIdx.x;  // NN*DD/8 = 160000 threads exactly
    int n = t >> 3, ch = t & 7;
    int base = n * DD + ch * 8;
    float4 m0 = *(const float4*)(m + base);
    float4 m1 = *(const float4*)(m + base + 4);
    float4 h0 = *(const float4*)(h + base);
    float4 h1 = *(const float4*)(h + base + 4);
    float mv[8] = {m0.x, m0.y, m0.z, m0.w, m1.x, m1.y, m1.z, m1.w};
    float hv[8] = {h0.x, h0.y, h0.z, h0.w, h1.x, h1.y, h1.z, h1.w};
    unsigned short hbv[8];
#pragma unroll
    for (int q = 0; q < 8; ++q) {
        int col = ch * 8 + q;
        float v = sp_(hv[q] + mv[q] * coeffN[col] + coeffN[64 + col]);
        hv[q] = v;
        hbv[q] = f2b(v);
    }
    float4 o0, o1;
    o0.x = hv[0]; o0.y = hv[1]; o0.z = hv[2]; o0.w = hv[3];
    o1.x = hv[4]; o1.y = hv[5]; o1.z = hv[6]; o1.w = hv[7];
    *(float4*)(h + base) = o0;
    *(float4*)(h + base + 4) = o1;
    if (fin) return;  // pooling handled by pool_seg_k from h

    bf16x8 hb8;
#pragma unroll
    for (int q = 0; q < 8; ++q) hb8[q] = (short)hbv[q];
    *(bf16x8*)(hb + base) = hb8;

    // fused zsum partials for next layer: rows use the bf16-ROUNDED values
    float oc = (float)ocnt[n], ic = (float)icnt[n];
    float zs8[8], zd8[8];
#pragma unroll
    for (int q = 0; q < 8; ++q) {
        float r = b2f(hbv[q]);
        zs8[q] = r * oc;
        zd8[q] = r * ic;
    }
    // reduce over the 8 node-rows within each wave (lane = nrow*8 + ch)
#pragma unroll
    for (int mk = 8; mk <= 32; mk <<= 1) {
#pragma unroll
        for (int q = 0; q < 8; ++q) {
            zs8[q] += __shfl_xor(zs8[q], mk, 64);
            zd8[q] += __shfl_xor(zd8[q], mk, 64);
        }
    }
    int lane = threadIdx.x & 63;
    int w = threadIdx.x >> 6;
    if (lane < 8) {
#pragma unroll
        for (int q = 0; q < 8; ++q) {
            wzs[w][lane][q] = zs8[q];
            wzd[w][lane][q] = zd8[q];
        }
    }
    __syncthreads();
    if (threadIdx.x < 64) {
        int chh = threadIdx.x >> 3, qq = threadIdx.x & 7; // col = chh*8+qq = threadIdx.x
        float s = wzs[0][chh][qq] + wzs[1][chh][qq] + wzs[2][chh][qq] + wzs[3][chh][qq];
        float d = wzd[0][chh][qq] + wzd[1][chh][qq] + wzd[2][chh][qq] + wzd[3][chh][qq];
        zpart[(size_t)threadIdx.x * NHB + blockIdx.x] = s;
        zpart[(size_t)(64 + threadIdx.x) * NHB + blockIdx.x] = d;
    }
}

// ---------------- segmented pooling over sorted gid: no atomics ----------------
__global__ __launch_bounds__(256) void pool_seg_k(const float* __restrict__ h,
                                                  const int* __restrict__ gid,
                                                  float* __restrict__ pool,
                                                  float* __restrict__ pcnt) {
    __shared__ int s_lo, s_hi;
    __shared__ float red[4][DD];
    int g = blockIdx.x;
    if (threadIdx.x == 0) {
        int lo = 0, hi = NN;
        while (lo < hi) { int mid = (lo + hi) >> 1; if (gid[mid] < g) lo = mid + 1; else hi = mid; }
        s_lo = lo;
        int lo2 = lo, hi2 = NN;
        while (lo2 < hi2) { int mid = (lo2 + hi2) >> 1; if (gid[mid] < g + 1) lo2 = mid + 1; else hi2 = mid; }
        s_hi = lo2;
    }
    __syncthreads();
    int lo = s_lo, hi = s_hi;
    int col = threadIdx.x & 63;
    int rr = threadIdx.x >> 6;
    float s = 0.f;
    for (int n = lo + rr; n < hi; n += 4) s += h[(size_t)n * DD + col];
    red[rr][col] = s;
    __syncthreads();
    if (threadIdx.x < 64) {
        float v = red[0][col] + red[1][col] + red[2][col] + red[3][col];
        pool[(size_t)g * DD + col] = v;
        if (col == 0) pcnt[g] = (float)(hi - lo);
    }
}

// ---------------- head ----------------
__global__ __launch_bounds__(128) void head_k(const float* __restrict__ pool,
                                              const float* __restrict__ pcnt,
                                              const float* __restrict__ fcW,
                                              const float* __restrict__ fcb,
                                              const float* __restrict__ oW,
                                              const float* __restrict__ ob,
                                              float* __restrict__ out) {
    int g = blockIdx.x;
    int t = threadIdx.x; // 128
    __shared__ float feats[DD];
    __shared__ float red[FF];
    if (t < DD) {
        float c = fmaxf(pcnt[g], 1.f);
        feats[t] = sp_(pool[(size_t)g * DD + t] / c);
    }
    __syncthreads();
    float a = fcb[t];
#pragma unroll 1
    for (int j = 0; j < DD; ++j) a += feats[j] * fcW[j * FF + t];
    float y = sp_(sp_(a));
    red[t] = y * oW[t];
    __syncthreads();
    for (int s2 = 64; s2 >= 1; s2 >>= 1) {
        if (t < s2) red[t] += red[t + s2];
        __syncthreads();
    }
    if (t == 0) out[g] = red[0] + ob[0];
}

extern "C" void kernel_launch(void* const* d_in, const int* in_sizes, int n_in,
                              void* d_out, int out_size, void* d_ws, size_t ws_size,
                              hipStream_t stream) {
    const float* af   = (const float*)d_in[0];
    const float* bond = (const float*)d_in[1];
    const int*   src  = (const int*)d_in[2];
    const int*   dst  = (const int*)d_in[3];
    const int*   gid  = (const int*)d_in[4];
    const float* embW = (const float*)d_in[5];
    const float* embB = (const float*)d_in[6];
    const float* Wi   = (const float*)d_in[7];
    const float* gi   = (const float*)d_in[9];
    const float* bbi  = (const float*)d_in[10];
    const float* Wu   = (const float*)d_in[11];
    const float* gu   = (const float*)d_in[13];
    const float* bbu  = (const float*)d_in[14];
    const float* gn   = (const float*)d_in[15];
    const float* bbn  = (const float*)d_in[16];
    const float* fcW  = (const float*)d_in[17];
    const float* fcb  = (const float*)d_in[18];
    const float* oW   = (const float*)d_in[19];
    const float* ob   = (const float*)d_in[20];
    float* out = (float*)d_out;

    char* ws = (char*)d_ws;
    size_t off = 0;
    auto take = [&](size_t bytes) {
        size_t o = off;
        off += (bytes + 255) & ~(size_t)255;
        return o;
    };
    float* h     = (float*)(ws + take((size_t)NN * DD * 4));
    float* m     = (float*)(ws + take((size_t)NN * DD * 4));
    float* stats = (float*)(ws + take(512 * 4));
    float* coeff = (float*)(ws + take(512 * 4)); // [sI,tI,sU,tU | sN,tN]
    float* pq    = (float*)(ws + take((size_t)2 * 64 * NBLK * 4)); // 2.56 MB partial sumsq
    float* mpart = (float*)(ws + take((size_t)128 * NAB * 4));     // 1.28 MB m-stat partials
    float* zpart = (float*)(ws + take((size_t)128 * NHB * 4));     // 320 KB zsum partials
    float* pool  = (float*)(ws + take((size_t)NG * DD * 4)); // 32768 B
    float* pcnt  = (float*)(ws + take((size_t)NG * 4));
    int* ecount  = (int*)(ws + take((size_t)NN * 4));        // indeg
    int* ocount  = (int*)(ws + take((size_t)NN * 4));        // outdeg (contiguous after ecount)
    int* eoff    = (int*)(ws + take((size_t)(NN + 1) * 4));
    int* ecur    = (int*)(ws + take((size_t)NN * 4));
    int* ssrc    = (int*)(ws + take((size_t)NE * 4));
    int* sdst    = (int*)(ws + take((size_t)NE * 4));
    float* bond_s = (float*)(ws + take((size_t)NE * 4));
    unsigned short* hb    = (unsigned short*)(ws + take((size_t)NN * DD * 2));
    unsigned short* preIb = (unsigned short*)(ws + take((size_t)NE * DD * 2));
    unsigned short* preUb = (unsigned short*)(ws + take((size_t)NE * DD * 2));
    unsigned short* Wf    = (unsigned short*)(ws + take((size_t)6 * 10240 * 2));

    // zero: ecount+ocount (contiguous), stats
    hipMemsetAsync((void*)ecount, 0, 2 * (((size_t)NN * 4 + 255) & ~(size_t)255), stream);
    hipMemsetAsync((void*)stats, 0, 512 * 4, stream);

    prep_wf_k<<<6, 256, 0, stream>>>(Wi, Wu, Wf);
    embed_k<<<NN / 32, 256, 0, stream>>>(af, embW, embB, h, hb);

    cnt_edges_k<<<(NE + 255) / 256, 256, 0, stream>>>(src, dst, ecount, ocount);
    csr_scan_k<<<1, 1024, 0, stream>>>(ecount, eoff, ecur);
    fill_edges_k<<<(NE + 255) / 256, 256, 0, stream>>>(src, dst, bond, ecur, ssrc, sdst, bond_s);
    rbfsum_k<<<512, 256, 0, stream>>>(bond, stats + 384);
    zsum_node_k<<<128, 256, 0, stream>>>(hb, ocount, ecount, stats + 256, stats + 320);

    for (int l = 0; l < 3; ++l) {
        const unsigned short* Wfl = Wf + (size_t)l * 2 * 10240;
        edge_pre2_k<<<2 * NBLK, 256, 0, stream>>>(hb, bond_s, Wfl, ssrc, sdst, preIb, preUb, pq);
        red_k<<<128, 256, 0, stream>>>(pq, stats, NBLK);
        fin_iu_k<<<1, 64, 0, stream>>>(stats, Wfl, gi + l * DD, bbi + l * DD,
                                       gu + l * DD, bbu + l * DD, coeff);
        apply_node_k<<<NAB, 256, 0, stream>>>(preIb, preUb, eoff, coeff, m, mpart);
        red_k<<<128, 256, 0, stream>>>(mpart, stats + 128, NAB);
        fin_n_k<<<1, 64, 0, stream>>>(stats, gn + l * DD, bbn + l * DD, coeff + 256);
        h_update_k<<<NHB, 256, 0, stream>>>(h, hb, m, coeff + 256, ocount, ecount,
                                            zpart, l == 2 ? 1 : 0);
        if (l < 2) red_k<<<128, 256, 0, stream>>>(zpart, stats + 256, NHB);
    }

    pool_seg_k<<<NG, 256, 0, stream>>>(h, gid, pool, pcnt);
    head_k<<<NG, 128, 0, stream>>>(pool, pcnt, fcW, fcb, oW, ob, out);
}